// Round 1
// baseline (3314.690 us; speedup 1.0000x reference)
//
#include <hip/hip_runtime.h>

// ---------------------------------------------------------------------------
// Problem constants (match reference)
// ---------------------------------------------------------------------------
#define F0 256
#define HD 128
#define ALPHA 0.2f
#define EPS_BN 1e-5f
#define EPS_LN 1e-5f

// ---------------------------------------------------------------------------
// CSR build
// ---------------------------------------------------------------------------
__global__ void k_hist(const int* __restrict__ row, int* __restrict__ counts, int E) {
    int e = blockIdx.x * blockDim.x + threadIdx.x;
    if (e < E) atomicAdd(&counts[row[e]], 1);
}

// single-block inclusive scan -> row_ptr (row_ptr[0]=0, row_ptr[i+1]=sum counts[0..i])
__global__ void k_scan(const int* __restrict__ counts, int* __restrict__ row_ptr, int n) {
    __shared__ int wsum[16];
    __shared__ int carry;
    int t = threadIdx.x;
    if (t == 0) { carry = 0; row_ptr[0] = 0; }
    __syncthreads();
    for (int base = 0; base < n; base += 1024) {
        int i = base + t;
        int v = (i < n) ? counts[i] : 0;
        int lane = t & 63, w = t >> 6;
        #pragma unroll
        for (int off = 1; off < 64; off <<= 1) {
            int u = __shfl_up(v, off);
            if (lane >= off) v += u;
        }
        if (lane == 63) wsum[w] = v;
        __syncthreads();
        if (t < 16) {
            int s = wsum[t];
            #pragma unroll
            for (int off = 1; off < 16; off <<= 1) {
                int u = __shfl_up(s, off);
                if (t >= off) s += u;
            }
            wsum[t] = s;
        }
        __syncthreads();
        int add = carry + (w > 0 ? wsum[w - 1] : 0);
        if (i < n) row_ptr[i + 1] = v + add;
        int total = wsum[15];
        __syncthreads();
        if (t == 0) carry += total;
        __syncthreads();
    }
}

__global__ void k_scatter(const int* __restrict__ row, const int* __restrict__ col,
                          const float* __restrict__ vals, const int* __restrict__ row_ptr,
                          int* __restrict__ cursor, int* __restrict__ col_s,
                          float* __restrict__ val_s, int E) {
    int e = blockIdx.x * blockDim.x + threadIdx.x;
    if (e >= E) return;
    int r = row[e];
    int pos = row_ptr[r] + atomicAdd(&cursor[r], 1);
    col_s[pos] = col[e];
    val_s[pos] = vals[e];
}

// ---------------------------------------------------------------------------
// SpMM, wave-per-row. D=256: lane holds float4. Fused: AX, AX2 (of x), deg.
// ---------------------------------------------------------------------------
__global__ void k_spmm_x2(const float* __restrict__ X, const int* __restrict__ row_ptr,
                          const int* __restrict__ cols, const float* __restrict__ vals,
                          float* __restrict__ AX, float* __restrict__ AX2,
                          float* __restrict__ deg, int N) {
    int wid = blockIdx.x * (blockDim.x >> 6) + (threadIdx.x >> 6);
    if (wid >= N) return;
    int lane = threadIdx.x & 63;
    float4 ax = make_float4(0.f, 0.f, 0.f, 0.f);
    float4 a2 = make_float4(0.f, 0.f, 0.f, 0.f);
    float d = 0.f;
    int s = row_ptr[wid], e = row_ptr[wid + 1];
    for (int j = s; j < e; j += 64) {
        int cnt = min(64, e - j);
        int c = (j + lane < e) ? cols[j + lane] : 0;
        float v = (j + lane < e) ? vals[j + lane] : 0.f;
        for (int i = 0; i < cnt; ++i) {
            int ci = __shfl(c, i);
            float vi = __shfl(v, i);
            float4 xv = *(const float4*)(X + (size_t)ci * F0 + lane * 4);
            ax.x += vi * xv.x; ax.y += vi * xv.y; ax.z += vi * xv.z; ax.w += vi * xv.w;
            a2.x += vi * xv.x * xv.x; a2.y += vi * xv.y * xv.y;
            a2.z += vi * xv.z * xv.z; a2.w += vi * xv.w * xv.w;
            d += vi;
        }
    }
    *(float4*)(AX + (size_t)wid * F0 + lane * 4) = ax;
    *(float4*)(AX2 + (size_t)wid * F0 + lane * 4) = a2;
    if (lane == 0) deg[wid] = d;
}

// D=128 spmm: lane holds float2
__global__ void k_spmm128(const float* __restrict__ X, const int* __restrict__ row_ptr,
                          const int* __restrict__ cols, const float* __restrict__ vals,
                          float* __restrict__ OUT, int N) {
    int wid = blockIdx.x * (blockDim.x >> 6) + (threadIdx.x >> 6);
    if (wid >= N) return;
    int lane = threadIdx.x & 63;
    float2 acc = make_float2(0.f, 0.f);
    int s = row_ptr[wid], e = row_ptr[wid + 1];
    for (int j = s; j < e; j += 64) {
        int cnt = min(64, e - j);
        int c = (j + lane < e) ? cols[j + lane] : 0;
        float v = (j + lane < e) ? vals[j + lane] : 0.f;
        for (int i = 0; i < cnt; ++i) {
            int ci = __shfl(c, i);
            float vi = __shfl(v, i);
            float2 xv = *(const float2*)(X + (size_t)ci * HD + lane * 2);
            acc.x += vi * xv.x; acc.y += vi * xv.y;
        }
    }
    *(float2*)(OUT + (size_t)wid * HD + lane * 2) = acc;
}

// ---------------------------------------------------------------------------
// fp32 tiled GEMM: C[M,Ncol] (+)= A[M,K] @ W[K,Ncol].  64x64 tile, BK=16,
// 256 threads, 4x4 micro-tile. mode 0: C = AW (+bias if bias), mode 1: C += AW
// ---------------------------------------------------------------------------
__global__ __launch_bounds__(256) void k_gemm(
    const float* __restrict__ A, const float* __restrict__ W, float* __restrict__ C,
    const float* __restrict__ bias, int M, int K, int Ncol, int mode) {
    __shared__ __align__(16) float As[16][68];
    __shared__ __align__(16) float Bs[16][68];
    int t = threadIdx.x;
    int m0 = blockIdx.x * 64, n0 = blockIdx.y * 64;
    int tm = t >> 4, tn = t & 15;
    int ar = t >> 2, ak = (t & 3) * 4;
    int br = t >> 4, bc = (t & 15) * 4;
    int arow = m0 + ar;
    float acc[4][4] = {};
    for (int k0 = 0; k0 < K; k0 += 16) {
        float4 av = make_float4(0.f, 0.f, 0.f, 0.f);
        if (arow < M) av = *(const float4*)(A + (size_t)arow * K + k0 + ak);
        float4 bv = *(const float4*)(W + (size_t)(k0 + br) * Ncol + n0 + bc);
        __syncthreads();
        As[ak + 0][ar] = av.x; As[ak + 1][ar] = av.y;
        As[ak + 2][ar] = av.z; As[ak + 3][ar] = av.w;
        *(float4*)&Bs[br][bc] = bv;
        __syncthreads();
        #pragma unroll
        for (int kk = 0; kk < 16; ++kk) {
            float4 a = *(const float4*)&As[kk][tm * 4];
            float4 b = *(const float4*)&Bs[kk][tn * 4];
            acc[0][0] += a.x * b.x; acc[0][1] += a.x * b.y; acc[0][2] += a.x * b.z; acc[0][3] += a.x * b.w;
            acc[1][0] += a.y * b.x; acc[1][1] += a.y * b.y; acc[1][2] += a.y * b.z; acc[1][3] += a.y * b.w;
            acc[2][0] += a.z * b.x; acc[2][1] += a.z * b.y; acc[2][2] += a.z * b.z; acc[2][3] += a.z * b.w;
            acc[3][0] += a.w * b.x; acc[3][1] += a.w * b.y; acc[3][2] += a.w * b.z; acc[3][3] += a.w * b.w;
        }
    }
    #pragma unroll
    for (int i = 0; i < 4; ++i) {
        int row = m0 + tm * 4 + i;
        if (row >= M) continue;
        float4 r = make_float4(acc[i][0], acc[i][1], acc[i][2], acc[i][3]);
        float* cp = C + (size_t)row * Ncol + n0 + tn * 4;
        if (mode == 1) {
            float4 o = *(const float4*)cp;
            r.x += o.x; r.y += o.y; r.z += o.z; r.w += o.w;
        } else if (bias) {
            float4 bb = *(const float4*)(bias + n0 + tn * 4);
            r.x += bb.x; r.y += bb.y; r.z += bb.z; r.w += bb.w;
        }
        *(float4*)cp = r;
    }
}

// ---------------------------------------------------------------------------
// BatchNorm: column sums (double) -> scale/shift -> apply+relu
// ---------------------------------------------------------------------------
__global__ void k_bn_stats(const float* __restrict__ H, double* __restrict__ stats,
                           int N, int C) {
    int t = threadIdx.x;
    int rpt = 256 / C;            // rows per block-iteration
    int rsub = t / C;
    int col = t - rsub * C;
    double s = 0.0, q = 0.0;
    for (long r = (long)blockIdx.x * rpt + rsub; r < N; r += (long)gridDim.x * rpt) {
        float v = H[(size_t)r * C + col];
        s += v; q += (double)v * v;
    }
    __shared__ double sh_s[256], sh_q[256];
    sh_s[t] = s; sh_q[t] = q;
    __syncthreads();
    if (t < C) {
        for (int k = 1; k < rpt; ++k) { s += sh_s[t + k * C]; q += sh_q[t + k * C]; }
        atomicAdd(&stats[t], s);
        atomicAdd(&stats[C + t], q);
    }
}

__global__ void k_bn_fin(const double* __restrict__ stats, const float* __restrict__ g,
                         const float* __restrict__ b, float* __restrict__ scale,
                         float* __restrict__ shift, int C, double invN) {
    int t = threadIdx.x;
    if (t >= C) return;
    double mean = stats[t] * invN;
    double var = stats[C + t] * invN - mean * mean;
    float sc = (float)((double)g[t] / sqrt(var + (double)EPS_BN));
    scale[t] = sc;
    shift[t] = b[t] - (float)mean * sc;
}

__global__ void k_bn_relu(const float* __restrict__ in, float* __restrict__ out,
                          const float* __restrict__ scale, const float* __restrict__ shift,
                          int total4, int cmask4) {
    int i = blockIdx.x * blockDim.x + threadIdx.x;
    if (i >= total4) return;
    int c4 = i & cmask4;
    float4 v = ((const float4*)in)[i];
    float4 sc = ((const float4*)scale)[c4];
    float4 sh = ((const float4*)shift)[c4];
    float4 r;
    r.x = fmaxf(v.x * sc.x + sh.x, 0.f);
    r.y = fmaxf(v.y * sc.y + sh.y, 0.f);
    r.z = fmaxf(v.z * sc.z + sh.z, 0.f);
    r.w = fmaxf(v.w * sc.w + sh.w, 0.f);
    ((float4*)out)[i] = r;
}

// ---------------------------------------------------------------------------
// Gating helpers
// ---------------------------------------------------------------------------
// x_std = sqrt(max(0, AX2/d - (AX/d)^2)), in place over AX2. d = deg+1e-8
__global__ void k_finalize_std(const float* __restrict__ AX, float* __restrict__ AX2,
                               const float* __restrict__ deg, int total4) {
    int i = blockIdx.x * blockDim.x + threadIdx.x;
    if (i >= total4) return;
    int r = (i * 4) >> 8;
    float inv = 1.0f / (deg[r] + 1e-8f);
    float4 ax = ((const float4*)AX)[i];
    float4 a2 = ((const float4*)AX2)[i];
    float4 m, v;
    m.x = ax.x * inv; m.y = ax.y * inv; m.z = ax.z * inv; m.w = ax.w * inv;
    v.x = sqrtf(fmaxf(a2.x * inv - m.x * m.x, 0.f));
    v.y = sqrtf(fmaxf(a2.y * inv - m.y * m.y, 0.f));
    v.z = sqrtf(fmaxf(a2.z * inv - m.z * m.z, 0.f));
    v.w = sqrtf(fmaxf(a2.w * inv - m.w * m.w, 0.f));
    ((float4*)AX2)[i] = v;
}

__global__ void k_prep_wd(const float* __restrict__ Wg1, float* __restrict__ Wd, int n) {
    int i = blockIdx.x * blockDim.x + threadIdx.x;
    if (i < n) Wd[i] = Wg1[i] - Wg1[n + i];
}

// Cg = bg1[c] + deg[r] * Wg1[768, c]
__global__ void k_gate_init(float* __restrict__ Cg, const float* __restrict__ bg1,
                            const float* __restrict__ Wg1_last, const float* __restrict__ deg,
                            int total4) {
    int i = blockIdx.x * blockDim.x + threadIdx.x;
    if (i >= total4) return;
    int r = (i * 4) >> 7;
    int c4 = i & 31;
    float d = deg[r];
    float4 w = ((const float4*)Wg1_last)[c4];
    float4 b = ((const float4*)bg1)[c4];
    float4 o;
    o.x = b.x + d * w.x; o.y = b.y + d * w.y; o.z = b.z + d * w.z; o.w = b.w + d * w.w;
    ((float4*)Cg)[i] = o;
}

// LayerNorm(+relu) over rows of 128, wave per row, in place
__global__ void k_ln_relu(float* __restrict__ H, const float* __restrict__ g,
                          const float* __restrict__ b, int N) {
    int wid = blockIdx.x * (blockDim.x >> 6) + (threadIdx.x >> 6);
    if (wid >= N) return;
    int lane = threadIdx.x & 63;
    float2 h = *(const float2*)(H + (size_t)wid * HD + lane * 2);
    float s1 = h.x + h.y, s2 = h.x * h.x + h.y * h.y;
    #pragma unroll
    for (int off = 32; off > 0; off >>= 1) { s1 += __shfl_xor(s1, off); s2 += __shfl_xor(s2, off); }
    float mu = s1 * (1.f / 128.f);
    float var = s2 * (1.f / 128.f) - mu * mu;
    float is = 1.0f / sqrtf(var + EPS_LN);
    float2 gg = *(const float2*)(g + lane * 2);
    float2 bb = *(const float2*)(b + lane * 2);
    float y0 = fmaxf((h.x - mu) * is * gg.x + bb.x, 0.f);
    float y1 = fmaxf((h.y - mu) * is * gg.y + bb.y, 0.f);
    *(float2*)(H + (size_t)wid * HD + lane * 2) = make_float2(y0, y1);
}

// residual = LN(res_scale*(R0 - low)) with rn_g/rn_b (R0 already includes bxp)
__global__ void k_resid_ln(float* __restrict__ R0, const float* __restrict__ low,
                           const float* __restrict__ g, const float* __restrict__ b,
                           const float* __restrict__ rs_ptr, int N) {
    int wid = blockIdx.x * (blockDim.x >> 6) + (threadIdx.x >> 6);
    if (wid >= N) return;
    int lane = threadIdx.x & 63;
    float rs = rs_ptr[0];
    float2 a = *(const float2*)(R0 + (size_t)wid * HD + lane * 2);
    float2 l = *(const float2*)(low + (size_t)wid * HD + lane * 2);
    float2 h = make_float2(rs * (a.x - l.x), rs * (a.y - l.y));
    float s1 = h.x + h.y, s2 = h.x * h.x + h.y * h.y;
    #pragma unroll
    for (int off = 32; off > 0; off >>= 1) { s1 += __shfl_xor(s1, off); s2 += __shfl_xor(s2, off); }
    float mu = s1 * (1.f / 128.f);
    float var = s2 * (1.f / 128.f) - mu * mu;
    float is = 1.0f / sqrtf(var + EPS_LN);
    float2 gg = *(const float2*)(g + lane * 2);
    float2 bb = *(const float2*)(b + lane * 2);
    float y0 = (h.x - mu) * is * gg.x + bb.x;
    float y1 = (h.y - mu) * is * gg.y + bb.y;
    *(float2*)(R0 + (size_t)wid * HD + lane * 2) = make_float2(y0, y1);
}

// gate = softmax((hg @ Wg2 + bg2)/2), wave per row
__global__ void k_gate(const float* __restrict__ hg, const float* __restrict__ Wg2,
                       const float* __restrict__ bg2, float* __restrict__ gate, int N) {
    int wid = blockIdx.x * (blockDim.x >> 6) + (threadIdx.x >> 6);
    if (wid >= N) return;
    int lane = threadIdx.x & 63;
    float2 h = *(const float2*)(hg + (size_t)wid * HD + lane * 2);
    float4 w = ((const float4*)Wg2)[lane];   // rows 2l, 2l+1 of [128,2]
    float s0 = h.x * w.x + h.y * w.z;
    float s1 = h.x * w.y + h.y * w.w;
    #pragma unroll
    for (int off = 32; off > 0; off >>= 1) { s0 += __shfl_xor(s0, off); s1 += __shfl_xor(s1, off); }
    if (lane == 0) {
        s0 = (s0 + bg2[0]) * 0.5f;
        s1 = (s1 + bg2[1]) * 0.5f;
        float m = fmaxf(s0, s1);
        float e0 = __expf(s0 - m), e1 = __expf(s1 - m);
        float inv = 1.0f / (e0 + e1);
        gate[(size_t)wid * 2 + 0] = e0 * inv;
        gate[(size_t)wid * 2 + 1] = e1 * inv;
    }
}

// fused GAT attention: wave per row; high = sum(e*V[col]) / (sum(e)+1e-16)
__global__ void k_attn(const float* __restrict__ Q, const float* __restrict__ K,
                       const float* __restrict__ V, const int* __restrict__ row_ptr,
                       const int* __restrict__ cols, float* __restrict__ high, int N) {
    int wid = blockIdx.x * (blockDim.x >> 6) + (threadIdx.x >> 6);
    if (wid >= N) return;
    int lane = threadIdx.x & 63;
    const float scl = 0.08838834764831845f;  // 1/sqrt(128)
    float2 q = *(const float2*)(Q + (size_t)wid * HD + lane * 2);
    float2 num = make_float2(0.f, 0.f);
    float den = 0.f;
    int s = row_ptr[wid], e = row_ptr[wid + 1];
    for (int j = s; j < e; j += 64) {
        int cnt = min(64, e - j);
        int c = (j + lane < e) ? cols[j + lane] : 0;
        for (int i = 0; i < cnt; ++i) {
            int ci = __shfl(c, i);
            float2 k2 = *(const float2*)(K + (size_t)ci * HD + lane * 2);
            float p = q.x * k2.x + q.y * k2.y;
            #pragma unroll
            for (int off = 32; off > 0; off >>= 1) p += __shfl_xor(p, off);
            float sc = p * scl;
            float ls = sc > 0.f ? sc : ALPHA * sc;
            float es = __expf(ls);
            float2 v2 = *(const float2*)(V + (size_t)ci * HD + lane * 2);
            num.x += es * v2.x; num.y += es * v2.y;
            den += es;
        }
    }
    float inv = 1.0f / (den + 1e-16f);
    *(float2*)(high + (size_t)wid * HD + lane * 2) = make_float2(num.x * inv, num.y * inv);
}

// out = g0*low + g1*high
__global__ void k_out(const float* __restrict__ gate, const float* __restrict__ low,
                      const float* __restrict__ high, float* __restrict__ out, int total4) {
    int i = blockIdx.x * blockDim.x + threadIdx.x;
    if (i >= total4) return;
    int r = i >> 5;  // 32 float4 per row of 128
    float g0 = gate[(size_t)r * 2 + 0], g1 = gate[(size_t)r * 2 + 1];
    float4 l = ((const float4*)low)[i];
    float4 h = ((const float4*)high)[i];
    float4 o;
    o.x = g0 * l.x + g1 * h.x; o.y = g0 * l.y + g1 * h.y;
    o.z = g0 * l.z + g1 * h.z; o.w = g0 * l.w + g1 * h.w;
    ((float4*)out)[i] = o;
}

// ---------------------------------------------------------------------------
extern "C" void kernel_launch(void* const* d_in, const int* in_sizes, int n_in,
                              void* d_out, int out_size, void* d_ws, size_t ws_size,
                              hipStream_t stream) {
    const float* x      = (const float*)d_in[0];
    const int*   erow   = (const int*)d_in[1];
    const int*   ecol   = (const int*)d_in[2];
    const float* avals  = (const float*)d_in[3];
    const float* W_gc1  = (const float*)d_in[4];
    const float* bn1_g  = (const float*)d_in[6];
    const float* bn1_b  = (const float*)d_in[7];
    const float* W_gc2  = (const float*)d_in[8];
    const float* bn2_g  = (const float*)d_in[10];
    const float* bn2_b  = (const float*)d_in[11];
    const float* Wg1    = (const float*)d_in[12];
    const float* bg1    = (const float*)d_in[13];
    const float* ln_g   = (const float*)d_in[14];
    const float* ln_b   = (const float*)d_in[15];
    const float* Wg2    = (const float*)d_in[16];
    const float* bg2    = (const float*)d_in[17];
    const float* Wxp    = (const float*)d_in[18];
    const float* bxp    = (const float*)d_in[19];
    const float* rscale = (const float*)d_in[20];
    const float* rn_g   = (const float*)d_in[21];
    const float* rn_b   = (const float*)d_in[22];
    const float* Wq     = (const float*)d_in[23];
    const float* Wk     = (const float*)d_in[24];
    const float* Wv     = (const float*)d_in[25];

    const int N = in_sizes[0] / F0;        // 100000
    const int E = in_sizes[1];             // 3200000

    // ---- workspace layout (float units) ----
    float* ws = (float*)d_ws;
    size_t o = 0;
    double* stats  = (double*)(ws + o);      o += 1024;        // 512 doubles
    float* scaleb  = ws + o;                 o += 256;
    float* shiftb  = ws + o;                 o += 256;
    float* Wd      = ws + o;                 o += 32768;       // Wg1a - Wg1b
    int*   row_ptr = (int*)(ws + o);         o += 100004;      // N+1
    int*   cursor  = (int*)(ws + o);         o += (size_t)N;   // counts, then cursor
    float* deg     = ws + o;                 o += (size_t)N;
    int*   col_s   = (int*)(ws + o);         o += (size_t)E;
    float* val_s   = ws + o;                 o += (size_t)E;
    float* AX      = ws + o;                 o += (size_t)N * F0;
    float* XSTD    = ws + o;                 o += (size_t)N * F0;  // AX2 -> x_std
    float* BIG3    = ws + o;                 o += (size_t)N * F0;  // S1/h1 -> R0/residual
    float* M1      = ws + o;                 o += (size_t)N * HD;  // G2 -> K
    float* M2      = ws + o;                 o += (size_t)N * HD;  // S2 -> V
    float* M3      = ws + o;                 o += (size_t)N * HD;  // Cg/hg -> Q
    (void)ws_size;

    // ---- output layout: [output | gate | low | high] ----
    float* out_o    = (float*)d_out;
    float* out_gate = out_o + (size_t)N * HD;
    float* out_low  = out_gate + (size_t)N * 2;
    float* out_high = out_low + (size_t)N * HD;

    const int eb = (E + 255) / 256;
    const int wb = (N + 3) / 4;            // wave-per-row blocks (256 thr)
    const dim3 blk(256);

    // ===== Phase 0: CSR build =====
    hipMemsetAsync(cursor, 0, (size_t)N * 4, stream);
    k_hist<<<eb, blk, 0, stream>>>(erow, cursor, E);
    k_scan<<<1, 1024, 0, stream>>>(cursor, row_ptr, N);
    hipMemsetAsync(cursor, 0, (size_t)N * 4, stream);
    k_scatter<<<eb, blk, 0, stream>>>(erow, ecol, avals, row_ptr, cursor, col_s, val_s, E);

    // ===== Phase 1: fused spmm over x -> AX, AX2, deg =====
    k_spmm_x2<<<wb, blk, 0, stream>>>(x, row_ptr, col_s, val_s, AX, XSTD, deg, N);
    k_finalize_std<<<(N * 64 + 255) / 256, blk, 0, stream>>>(AX, XSTD, deg, N * 64);

    // ===== Phase 2: low path =====
    // S1 = AX @ W_gc1   (spmm/gemm reassociation; BN is bias-invariant)
    {
        dim3 g((N + 63) / 64, 4);
        k_gemm<<<g, blk, 0, stream>>>(AX, W_gc1, BIG3, nullptr, N, 256, 256, 0);
    }
    hipMemsetAsync(stats, 0, 4096, stream);
    k_bn_stats<<<1024, blk, 0, stream>>>(BIG3, stats, N, 256);
    k_bn_fin<<<1, blk, 0, stream>>>(stats, bn1_g, bn1_b, scaleb, shiftb, 256, 1.0 / N);
    k_bn_relu<<<(N * 64 + 255) / 256, blk, 0, stream>>>(BIG3, BIG3, scaleb, shiftb, N * 64, 63);
    // G2 = h1 @ W_gc2 ; S2 = spmm(G2) ; low = relu(BN(S2))
    {
        dim3 g((N + 63) / 64, 2);
        k_gemm<<<g, blk, 0, stream>>>(BIG3, W_gc2, M1, nullptr, N, 256, 128, 0);
    }
    k_spmm128<<<wb, blk, 0, stream>>>(M1, row_ptr, col_s, val_s, M2, N);
    hipMemsetAsync(stats, 0, 2048, stream);
    k_bn_stats<<<1024, blk, 0, stream>>>(M2, stats, N, 128);
    k_bn_fin<<<1, blk, 0, stream>>>(stats, bn2_g, bn2_b, scaleb, shiftb, 128, 1.0 / N);
    k_bn_relu<<<(N * 32 + 255) / 256, blk, 0, stream>>>(M2, out_low, scaleb, shiftb, N * 32, 31);

    // ===== Phase 3: gating =====
    k_prep_wd<<<128, blk, 0, stream>>>(Wg1, Wd, 32768);
    k_gate_init<<<(N * 32 + 255) / 256, blk, 0, stream>>>(M3, bg1, Wg1 + (size_t)768 * 128, deg, N * 32);
    {
        dim3 g((N + 63) / 64, 2);
        k_gemm<<<g, blk, 0, stream>>>(x, Wd, M3, nullptr, N, 256, 128, 1);
        k_gemm<<<g, blk, 0, stream>>>(AX, Wg1 + (size_t)256 * 128, M3, nullptr, N, 256, 128, 1);
        k_gemm<<<g, blk, 0, stream>>>(XSTD, Wg1 + (size_t)512 * 128, M3, nullptr, N, 256, 128, 1);
    }
    k_ln_relu<<<wb, blk, 0, stream>>>(M3, ln_g, ln_b, N);
    k_gate<<<wb, blk, 0, stream>>>(M3, Wg2, bg2, out_gate, N);

    // ===== Phase 4: high path =====
    {
        dim3 g((N + 63) / 64, 2);
        k_gemm<<<g, blk, 0, stream>>>(x, Wxp, BIG3, bxp, N, 256, 128, 0);  // R0 = x@Wxp + bxp
    }
    k_resid_ln<<<wb, blk, 0, stream>>>(BIG3, out_low, rn_g, rn_b, rscale, N);
    {
        dim3 g((N + 63) / 64, 2);
        k_gemm<<<g, blk, 0, stream>>>(BIG3, Wq, M3, nullptr, N, 128, 128, 0);
        k_gemm<<<g, blk, 0, stream>>>(BIG3, Wk, M1, nullptr, N, 128, 128, 0);
        k_gemm<<<g, blk, 0, stream>>>(BIG3, Wv, M2, nullptr, N, 128, 128, 0);
    }
    k_attn<<<wb, blk, 0, stream>>>(M3, M1, M2, row_ptr, col_s, out_high, N);

    // ===== Phase 5: combine =====
    k_out<<<(N * 32 + 255) / 256, blk, 0, stream>>>(out_gate, out_low, out_high, out_o, N * 32);
}

// Round 2
// 2040.417 us; speedup vs baseline: 1.6245x; 1.6245x over previous
//
#include <hip/hip_runtime.h>

#define F0 256
#define HD 128
#define NP 100352   // padded rows (782*128=100096 rounded up)

typedef unsigned short u16;
typedef __attribute__((ext_vector_type(8))) short short8;
typedef __attribute__((ext_vector_type(4))) float f32x4;

__device__ inline float bf2f(u16 u) {
    union { unsigned int i; float f; } v; v.i = ((unsigned int)u) << 16; return v.f;
}
__device__ inline u16 f2bf(float f) {
    union { float f; unsigned int i; } v; v.f = f;
    unsigned int r = v.i + 0x7FFF + ((v.i >> 16) & 1);
    return (u16)(r >> 16);
}

#define GLOAD16(gp, lp) __builtin_amdgcn_global_load_lds( \
    (const __attribute__((address_space(1))) void*)(gp), \
    (__attribute__((address_space(3))) void*)(lp), 16, 0, 0)

// ---------------------------------------------------------------------------
// CSR build
// ---------------------------------------------------------------------------
__global__ void k_hist(const int* __restrict__ row, int* __restrict__ counts, int E) {
    int e = blockIdx.x * blockDim.x + threadIdx.x;
    if (e < E) atomicAdd(&counts[row[e]], 1);
}

__global__ void k_scan_blk(const int* __restrict__ counts, int* __restrict__ scan_out,
                           int* __restrict__ partials, int n) {
    __shared__ int wsum[16];
    int t = threadIdx.x;
    int i = blockIdx.x * 1024 + t;
    int v = (i < n) ? counts[i] : 0;
    int lane = t & 63, w = t >> 6;
    #pragma unroll
    for (int off = 1; off < 64; off <<= 1) { int u = __shfl_up(v, off); if (lane >= off) v += u; }
    if (lane == 63) wsum[w] = v;
    __syncthreads();
    if (t < 16) {
        int s = wsum[t];
        #pragma unroll
        for (int off = 1; off < 16; off <<= 1) { int u = __shfl_up(s, off); if (t >= off) s += u; }
        wsum[t] = s;
    }
    __syncthreads();
    int add = (w > 0) ? wsum[w - 1] : 0;
    if (i < n) scan_out[i] = v + add;
    if (t == 1023) partials[blockIdx.x] = wsum[15];
}

__global__ void k_scan_part(int* partials, int nb) {
    __shared__ int ws2[2];
    int t = threadIdx.x;
    int v = (t < nb) ? partials[t] : 0;
    int lane = t & 63, w = t >> 6;
    #pragma unroll
    for (int off = 1; off < 64; off <<= 1) { int u = __shfl_up(v, off); if (lane >= off) v += u; }
    if (lane == 63) ws2[w] = v;
    __syncthreads();
    if (w == 1) v += ws2[0];
    if (t < nb) partials[t] = v;
}

__global__ void k_scan_add(int* __restrict__ row_ptr, const int* __restrict__ partials, int n) {
    int b = blockIdx.x;
    int i = b * 1024 + threadIdx.x;
    if (b == 0 && threadIdx.x == 0) row_ptr[0] = 0;
    int add = (b > 0) ? partials[b - 1] : 0;
    if (i < n) row_ptr[1 + i] += add;
}

__global__ void k_scatter(const int* __restrict__ row, const int* __restrict__ col,
                          const float* __restrict__ vals, const int* __restrict__ row_ptr,
                          int* __restrict__ cursor, int* __restrict__ row_s,
                          int* __restrict__ col_s, float* __restrict__ val_s, int E) {
    int e = blockIdx.x * blockDim.x + threadIdx.x;
    if (e >= E) return;
    int r = row[e];
    int pos = row_ptr[r] + atomicAdd(&cursor[r], 1);
    row_s[pos] = r;
    col_s[pos] = col[e];
    val_s[pos] = vals[e];
}

// ---------------------------------------------------------------------------
// casts
// ---------------------------------------------------------------------------
__global__ void k_cast_x(const float* __restrict__ x, u16* __restrict__ xb, int total4) {
    int i = blockIdx.x * blockDim.x + threadIdx.x;
    if (i >= total4) return;
    float4 v = ((const float4*)x)[i];
    ((ushort4*)xb)[i] = make_ushort4(f2bf(v.x), f2bf(v.y), f2bf(v.z), f2bf(v.w));
}

// cast + transpose all weights to bf16 [N][K]
__global__ void k_prep_w(const float* __restrict__ W_gc1, const float* __restrict__ W_gc2,
                         const float* __restrict__ Wg1, const float* __restrict__ Wxp,
                         const float* __restrict__ Wq, const float* __restrict__ Wk,
                         const float* __restrict__ Wv,
                         u16* Wgc1t, u16* Wgc2t, u16* Wdt, u16* W1t, u16* W2t,
                         u16* Wxpt, u16* Wqt, u16* Wkt, u16* Wvt) {
    int z = blockIdx.z;
    int idx = blockIdx.x * 256 + threadIdx.x;
    if (z == 0) { if (idx < 65536) { int n = idx >> 8, k = idx & 255; Wgc1t[idx] = f2bf(W_gc1[k * 256 + n]); } }
    else if (z == 1) { if (idx < 32768) { int n = idx >> 8, k = idx & 255; Wgc2t[idx] = f2bf(W_gc2[k * 128 + n]); } }
    else if (z == 2) { if (idx < 32768) { int n = idx >> 8, k = idx & 255; Wdt[idx] = f2bf(Wg1[k * 128 + n] - Wg1[(k + 256) * 128 + n]); } }
    else if (z == 3) { if (idx < 32768) { int n = idx >> 8, k = idx & 255; W1t[idx] = f2bf(Wg1[(k + 256) * 128 + n]); } }
    else if (z == 4) { if (idx < 32768) { int n = idx >> 8, k = idx & 255; W2t[idx] = f2bf(Wg1[(k + 512) * 128 + n]); } }
    else if (z == 5) { if (idx < 32768) { int n = idx >> 8, k = idx & 255; Wxpt[idx] = f2bf(Wxp[k * 128 + n]); } }
    else if (z == 6) { if (idx < 16384) { int n = idx >> 7, k = idx & 127; Wqt[idx] = f2bf(Wq[k * 128 + n]); } }
    else if (z == 7) { if (idx < 16384) { int n = idx >> 7, k = idx & 127; Wkt[idx] = f2bf(Wk[k * 128 + n]); } }
    else if (z == 8) { if (idx < 16384) { int n = idx >> 7, k = idx & 127; Wvt[idx] = f2bf(Wv[k * 128 + n]); } }
}

// ---------------------------------------------------------------------------
// SpMM (bf16 X gather, uniform broadcast loads, unroll-2)
// ---------------------------------------------------------------------------
__global__ void k_spmm_x2(const u16* __restrict__ Xb, const int* __restrict__ row_ptr,
                          const int* __restrict__ cols, const float* __restrict__ vals,
                          float* __restrict__ AX, float* __restrict__ AX2,
                          float* __restrict__ deg, int N) {
    int wid = blockIdx.x * 4 + (threadIdx.x >> 6);
    if (wid >= N) return;
    int lane = threadIdx.x & 63;
    float a0 = 0, a1 = 0, a2 = 0, a3 = 0;
    float q0 = 0, q1 = 0, q2 = 0, q3 = 0, d = 0;
    int s = row_ptr[wid], e = row_ptr[wid + 1];
    int j = s;
    for (; j + 1 < e; j += 2) {
        int c0 = cols[j], c1 = cols[j + 1];
        float v0 = vals[j], v1 = vals[j + 1];
        ushort4 xb0 = *(const ushort4*)(Xb + (size_t)c0 * F0 + lane * 4);
        ushort4 xb1 = *(const ushort4*)(Xb + (size_t)c1 * F0 + lane * 4);
        float x0 = bf2f(xb0.x), x1 = bf2f(xb0.y), x2 = bf2f(xb0.z), x3 = bf2f(xb0.w);
        float y0 = bf2f(xb1.x), y1 = bf2f(xb1.y), y2 = bf2f(xb1.z), y3 = bf2f(xb1.w);
        a0 += v0 * x0 + v1 * y0; a1 += v0 * x1 + v1 * y1;
        a2 += v0 * x2 + v1 * y2; a3 += v0 * x3 + v1 * y3;
        q0 += v0 * x0 * x0 + v1 * y0 * y0; q1 += v0 * x1 * x1 + v1 * y1 * y1;
        q2 += v0 * x2 * x2 + v1 * y2 * y2; q3 += v0 * x3 * x3 + v1 * y3 * y3;
        d += v0 + v1;
    }
    if (j < e) {
        int c0 = cols[j]; float v0 = vals[j];
        ushort4 xb0 = *(const ushort4*)(Xb + (size_t)c0 * F0 + lane * 4);
        float x0 = bf2f(xb0.x), x1 = bf2f(xb0.y), x2 = bf2f(xb0.z), x3 = bf2f(xb0.w);
        a0 += v0 * x0; a1 += v0 * x1; a2 += v0 * x2; a3 += v0 * x3;
        q0 += v0 * x0 * x0; q1 += v0 * x1 * x1; q2 += v0 * x2 * x2; q3 += v0 * x3 * x3;
        d += v0;
    }
    *(float4*)(AX + (size_t)wid * F0 + lane * 4) = make_float4(a0, a1, a2, a3);
    *(float4*)(AX2 + (size_t)wid * F0 + lane * 4) = make_float4(q0, q1, q2, q3);
    if (lane == 0) deg[wid] = d;
}

__global__ void k_spmm128(const u16* __restrict__ Xb, const int* __restrict__ row_ptr,
                          const int* __restrict__ cols, const float* __restrict__ vals,
                          float* __restrict__ OUT, int N) {
    int wid = blockIdx.x * 4 + (threadIdx.x >> 6);
    if (wid >= N) return;
    int lane = threadIdx.x & 63;
    float a0 = 0, a1 = 0;
    int s = row_ptr[wid], e = row_ptr[wid + 1];
    int j = s;
    for (; j + 1 < e; j += 2) {
        int c0 = cols[j], c1 = cols[j + 1];
        float v0 = vals[j], v1 = vals[j + 1];
        ushort2 x0 = *(const ushort2*)(Xb + (size_t)c0 * HD + lane * 2);
        ushort2 x1 = *(const ushort2*)(Xb + (size_t)c1 * HD + lane * 2);
        a0 += v0 * bf2f(x0.x) + v1 * bf2f(x1.x);
        a1 += v0 * bf2f(x0.y) + v1 * bf2f(x1.y);
    }
    if (j < e) {
        int c0 = cols[j]; float v0 = vals[j];
        ushort2 x0 = *(const ushort2*)(Xb + (size_t)c0 * HD + lane * 2);
        a0 += v0 * bf2f(x0.x); a1 += v0 * bf2f(x0.y);
    }
    *(float2*)(OUT + (size_t)wid * HD + lane * 2) = make_float2(a0, a1);
}

// ---------------------------------------------------------------------------
// bf16 MFMA GEMM core: C[128,128] tile = A[M,K] @ Bt[N,K]^T, BK=32
// ---------------------------------------------------------------------------
__device__ inline void mm_core(const u16* __restrict__ A, const u16* __restrict__ Bt,
                               int K, int ldA, int ldB, int m0, int n0,
                               u16* As, u16* Bs, f32x4 acc[4][4]) {
    int t = threadIdx.x, w = t >> 6, l = t & 63;
    int wr = (w >> 1) * 64, wc = (w & 1) * 64;
    int aoff = (wr + (l & 15)) * 32 + (l >> 4) * 8;
    int boff = (wc + (l & 15)) * 32 + (l >> 4) * 8;
    for (int k0 = 0; k0 < K; k0 += 32) {
        __syncthreads();
        #pragma unroll
        for (int s = 0; s < 2; ++s) {
            int i = s * 256 + t;
            int row = i >> 2, ch = i & 3;
            GLOAD16(A + (size_t)(m0 + row) * ldA + k0 + ch * 8, As + i * 8);
            GLOAD16(Bt + (size_t)(n0 + row) * ldB + k0 + ch * 8, Bs + i * 8);
        }
        __syncthreads();
        short8 af[4], bfr[4];
        #pragma unroll
        for (int i = 0; i < 4; ++i) af[i] = *(const short8*)(As + aoff + i * 16 * 32);
        #pragma unroll
        for (int j = 0; j < 4; ++j) bfr[j] = *(const short8*)(Bs + boff + j * 16 * 32);
        #pragma unroll
        for (int i = 0; i < 4; ++i)
            #pragma unroll
            for (int j = 0; j < 4; ++j)
                acc[i][j] = __builtin_amdgcn_mfma_f32_16x16x32_bf16(af[i], bfr[j], acc[i][j], 0, 0, 0);
    }
}

__device__ inline void mm_zero(f32x4 acc[4][4]) {
    #pragma unroll
    for (int i = 0; i < 4; ++i)
        #pragma unroll
        for (int j = 0; j < 4; ++j)
            acc[i][j] = (f32x4){0.f, 0.f, 0.f, 0.f};
}

__global__ __launch_bounds__(256) void k_mm_f32(const u16* __restrict__ A, const u16* __restrict__ Bt,
                                                float* __restrict__ C, const float* __restrict__ bias,
                                                int M, int K, int Nc) {
    __shared__ __align__(16) u16 As[128 * 32];
    __shared__ __align__(16) u16 Bs[128 * 32];
    int m0 = blockIdx.x * 128, n0 = blockIdx.y * 128;
    f32x4 acc[4][4]; mm_zero(acc);
    mm_core(A, Bt, K, K, K, m0, n0, As, Bs, acc);
    int t = threadIdx.x, w = t >> 6, l = t & 63;
    int rbase = m0 + (w >> 1) * 64 + (l >> 4) * 4;
    int cbase = n0 + (w & 1) * 64 + (l & 15);
    #pragma unroll
    for (int j = 0; j < 4; ++j) {
        float bj = bias ? bias[cbase + j * 16] : 0.f;
        #pragma unroll
        for (int i = 0; i < 4; ++i)
            #pragma unroll
            for (int r = 0; r < 4; ++r) {
                int row = rbase + i * 16 + r;
                if (row < M) C[(size_t)row * Nc + cbase + j * 16] = acc[i][j][r] + bj;
            }
    }
}

__global__ __launch_bounds__(256) void k_mm_bf(const u16* __restrict__ A, const u16* __restrict__ Bt,
                                               u16* __restrict__ C, int M, int K, int Nc) {
    __shared__ __align__(16) u16 As[128 * 32];
    __shared__ __align__(16) u16 Bs[128 * 32];
    int m0 = blockIdx.x * 128, n0 = blockIdx.y * 128;
    f32x4 acc[4][4]; mm_zero(acc);
    mm_core(A, Bt, K, K, K, m0, n0, As, Bs, acc);
    int t = threadIdx.x, w = t >> 6, l = t & 63;
    int rbase = m0 + (w >> 1) * 64 + (l >> 4) * 4;
    int cbase = n0 + (w & 1) * 64 + (l & 15);
    #pragma unroll
    for (int j = 0; j < 4; ++j)
        #pragma unroll
        for (int i = 0; i < 4; ++i)
            #pragma unroll
            for (int r = 0; r < 4; ++r) {
                int row = rbase + i * 16 + r;
                if (row < M) C[(size_t)row * Nc + cbase + j * 16] = f2bf(acc[i][j][r]);
            }
}

// gate: C = x@Wd + AX@W1 + xstd@W2 + bg1 + deg*wlast   (Nc=128, K=256 each)
__global__ __launch_bounds__(256) void k_mm_gate(const u16* A0, const u16* A1, const u16* A2,
                                                 const u16* B0, const u16* B1, const u16* B2,
                                                 float* __restrict__ C, const float* __restrict__ bg1,
                                                 const float* __restrict__ wlast,
                                                 const float* __restrict__ deg, int M) {
    __shared__ __align__(16) u16 As[128 * 32];
    __shared__ __align__(16) u16 Bs[128 * 32];
    int m0 = blockIdx.x * 128;
    f32x4 acc[4][4]; mm_zero(acc);
    mm_core(A0, B0, 256, 256, 256, m0, 0, As, Bs, acc);
    mm_core(A1, B1, 256, 256, 256, m0, 0, As, Bs, acc);
    mm_core(A2, B2, 256, 256, 256, m0, 0, As, Bs, acc);
    int t = threadIdx.x, w = t >> 6, l = t & 63;
    int rbase = m0 + (w >> 1) * 64 + (l >> 4) * 4;
    int cbase = (w & 1) * 64 + (l & 15);
    float wl[4], bg[4];
    #pragma unroll
    for (int j = 0; j < 4; ++j) { wl[j] = wlast[cbase + j * 16]; bg[j] = bg1[cbase + j * 16]; }
    float dg[4][4];
    #pragma unroll
    for (int i = 0; i < 4; ++i)
        #pragma unroll
        for (int r = 0; r < 4; ++r) {
            int row = rbase + i * 16 + r;
            dg[i][r] = (row < M) ? deg[row] : 0.f;
        }
    #pragma unroll
    for (int j = 0; j < 4; ++j)
        #pragma unroll
        for (int i = 0; i < 4; ++i)
            #pragma unroll
            for (int r = 0; r < 4; ++r) {
                int row = rbase + i * 16 + r;
                if (row < M) C[(size_t)row * 128 + cbase + j * 16] = acc[i][j][r] + bg[j] + dg[i][r] * wl[j];
            }
}

__global__ __launch_bounds__(256) void k_mm_qkv(const u16* __restrict__ A,
                                                const u16* Wqt, const u16* Wkt, const u16* Wvt,
                                                float* Q, float* Kf, float* Vf, int M) {
    __shared__ __align__(16) u16 As[128 * 32];
    __shared__ __align__(16) u16 Bs[128 * 32];
    const u16* Bt = (blockIdx.z == 0) ? Wqt : (blockIdx.z == 1) ? Wkt : Wvt;
    float* C = (blockIdx.z == 0) ? Q : (blockIdx.z == 1) ? Kf : Vf;
    int m0 = blockIdx.x * 128;
    f32x4 acc[4][4]; mm_zero(acc);
    mm_core(A, Bt, 128, 128, 128, m0, 0, As, Bs, acc);
    int t = threadIdx.x, w = t >> 6, l = t & 63;
    int rbase = m0 + (w >> 1) * 64 + (l >> 4) * 4;
    int cbase = (w & 1) * 64 + (l & 15);
    #pragma unroll
    for (int j = 0; j < 4; ++j)
        #pragma unroll
        for (int i = 0; i < 4; ++i)
            #pragma unroll
            for (int r = 0; r < 4; ++r) {
                int row = rbase + i * 16 + r;
                if (row < M) C[(size_t)row * 128 + cbase + j * 16] = acc[i][j][r];
            }
}

// ---------------------------------------------------------------------------
// BatchNorm
// ---------------------------------------------------------------------------
__global__ void k_bn_stats(const float* __restrict__ H, double* __restrict__ stats, int N, int C) {
    int t = threadIdx.x;
    int rpt = 256 / C;
    int rsub = t / C;
    int col = t - rsub * C;
    double s = 0.0, q = 0.0;
    for (long r = (long)blockIdx.x * rpt + rsub; r < N; r += (long)gridDim.x * rpt) {
        float v = H[(size_t)r * C + col];
        s += v; q += (double)v * v;
    }
    __shared__ double sh_s[256], sh_q[256];
    sh_s[t] = s; sh_q[t] = q;
    __syncthreads();
    if (t < C) {
        for (int k = 1; k < rpt; ++k) { s += sh_s[t + k * C]; q += sh_q[t + k * C]; }
        atomicAdd(&stats[t], s);
        atomicAdd(&stats[C + t], q);
    }
}

__global__ void k_bn_fin(const double* __restrict__ stats, const float* __restrict__ g,
                         const float* __restrict__ b, float* __restrict__ scale,
                         float* __restrict__ shift, int C, double invN) {
    int t = threadIdx.x;
    if (t >= C) return;
    double mean = stats[t] * invN;
    double var = stats[C + t] * invN - mean * mean;
    float sc = (float)((double)g[t] / sqrt(var + 1e-5));
    scale[t] = sc;
    shift[t] = b[t] - (float)mean * sc;
}

__global__ void k_bn_relu_f(const float* __restrict__ in, float* __restrict__ out,
                            const float* __restrict__ scale, const float* __restrict__ shift,
                            int total4, int cmask4) {
    int i = blockIdx.x * blockDim.x + threadIdx.x;
    if (i >= total4) return;
    int c4 = i & cmask4;
    float4 v = ((const float4*)in)[i];
    float4 sc = ((const float4*)scale)[c4];
    float4 sh = ((const float4*)shift)[c4];
    ((float4*)out)[i] = make_float4(fmaxf(v.x * sc.x + sh.x, 0.f), fmaxf(v.y * sc.y + sh.y, 0.f),
                                    fmaxf(v.z * sc.z + sh.z, 0.f), fmaxf(v.w * sc.w + sh.w, 0.f));
}

__global__ void k_bn_relu_b(const float* __restrict__ in, u16* __restrict__ out,
                            const float* __restrict__ scale, const float* __restrict__ shift,
                            int total4, int cmask4) {
    int i = blockIdx.x * blockDim.x + threadIdx.x;
    if (i >= total4) return;
    int c4 = i & cmask4;
    float4 v = ((const float4*)in)[i];
    float4 sc = ((const float4*)scale)[c4];
    float4 sh = ((const float4*)shift)[c4];
    ((ushort4*)out)[i] = make_ushort4(f2bf(fmaxf(v.x * sc.x + sh.x, 0.f)), f2bf(fmaxf(v.y * sc.y + sh.y, 0.f)),
                                      f2bf(fmaxf(v.z * sc.z + sh.z, 0.f)), f2bf(fmaxf(v.w * sc.w + sh.w, 0.f)));
}

// ---------------------------------------------------------------------------
// gating helpers
// ---------------------------------------------------------------------------
__global__ void k_finalize(const float* __restrict__ AX, const float* __restrict__ AX2,
                           const float* __restrict__ deg, u16* __restrict__ AXb,
                           u16* __restrict__ XSTDb, int total4) {
    int i = blockIdx.x * blockDim.x + threadIdx.x;
    if (i >= total4) return;
    int r = i >> 6;
    float inv = 1.0f / (deg[r] + 1e-8f);
    float4 ax = ((const float4*)AX)[i];
    float4 a2 = ((const float4*)AX2)[i];
    float mx = ax.x * inv, my = ax.y * inv, mz = ax.z * inv, mw = ax.w * inv;
    float sx = sqrtf(fmaxf(a2.x * inv - mx * mx, 0.f));
    float sy = sqrtf(fmaxf(a2.y * inv - my * my, 0.f));
    float sz = sqrtf(fmaxf(a2.z * inv - mz * mz, 0.f));
    float sw = sqrtf(fmaxf(a2.w * inv - mw * mw, 0.f));
    ((ushort4*)AXb)[i] = make_ushort4(f2bf(ax.x), f2bf(ax.y), f2bf(ax.z), f2bf(ax.w));
    ((ushort4*)XSTDb)[i] = make_ushort4(f2bf(sx), f2bf(sy), f2bf(sz), f2bf(sw));
}

// fused LN + relu + 128->2 matvec + softmax -> gate
__global__ void k_ln_gate(const float* __restrict__ Hg, const float* __restrict__ g,
                          const float* __restrict__ b, const float* __restrict__ Wg2,
                          const float* __restrict__ bg2, float* __restrict__ gate, int N) {
    int wid = blockIdx.x * 4 + (threadIdx.x >> 6);
    if (wid >= N) return;
    int lane = threadIdx.x & 63;
    float2 h = *(const float2*)(Hg + (size_t)wid * HD + lane * 2);
    float s1 = h.x + h.y, s2 = h.x * h.x + h.y * h.y;
    #pragma unroll
    for (int off = 32; off > 0; off >>= 1) { s1 += __shfl_xor(s1, off); s2 += __shfl_xor(s2, off); }
    float mu = s1 * (1.f / 128.f);
    float var = s2 * (1.f / 128.f) - mu * mu;
    float is = 1.0f / sqrtf(var + 1e-5f);
    float2 gg = *(const float2*)(g + lane * 2);
    float2 bb = *(const float2*)(b + lane * 2);
    float y0 = fmaxf((h.x - mu) * is * gg.x + bb.x, 0.f);
    float y1 = fmaxf((h.y - mu) * is * gg.y + bb.y, 0.f);
    float4 w = ((const float4*)Wg2)[lane];
    float t0 = y0 * w.x + y1 * w.z;
    float t1 = y0 * w.y + y1 * w.w;
    #pragma unroll
    for (int off = 32; off > 0; off >>= 1) { t0 += __shfl_xor(t0, off); t1 += __shfl_xor(t1, off); }
    if (lane == 0) {
        t0 = (t0 + bg2[0]) * 0.5f;
        t1 = (t1 + bg2[1]) * 0.5f;
        float m = fmaxf(t0, t1);
        float e0 = __expf(t0 - m), e1 = __expf(t1 - m);
        float inv = 1.0f / (e0 + e1);
        gate[(size_t)wid * 2 + 0] = e0 * inv;
        gate[(size_t)wid * 2 + 1] = e1 * inv;
    }
}

// residual = LN(rs*(R0 - low)) -> bf16
__global__ void k_resid_ln(const float* __restrict__ R0, const float* __restrict__ low,
                           const float* __restrict__ g, const float* __restrict__ b,
                           const float* __restrict__ rs_ptr, u16* __restrict__ resid, int N) {
    int wid = blockIdx.x * 4 + (threadIdx.x >> 6);
    if (wid >= N) return;
    int lane = threadIdx.x & 63;
    float rs = rs_ptr[0];
    float2 a = *(const float2*)(R0 + (size_t)wid * HD + lane * 2);
    float2 l = *(const float2*)(low + (size_t)wid * HD + lane * 2);
    float h0 = rs * (a.x - l.x), h1 = rs * (a.y - l.y);
    float s1 = h0 + h1, s2 = h0 * h0 + h1 * h1;
    #pragma unroll
    for (int off = 32; off > 0; off >>= 1) { s1 += __shfl_xor(s1, off); s2 += __shfl_xor(s2, off); }
    float mu = s1 * (1.f / 128.f);
    float var = s2 * (1.f / 128.f) - mu * mu;
    float is = 1.0f / sqrtf(var + 1e-5f);
    float2 gg = *(const float2*)(g + lane * 2);
    float2 bb = *(const float2*)(b + lane * 2);
    float y0 = (h0 - mu) * is * gg.x + bb.x;
    float y1 = (h1 - mu) * is * gg.y + bb.y;
    *(ushort2*)(resid + (size_t)wid * HD + lane * 2) = make_ushort2(f2bf(y0), f2bf(y1));
}

// edge-parallel scores: 16 lanes per edge
__global__ void k_score(const float* __restrict__ Q, const float* __restrict__ Kf,
                        const int* __restrict__ rows, const int* __restrict__ cols,
                        float* __restrict__ exps, int E) {
    int t = threadIdx.x;
    int e = blockIdx.x * 16 + (t >> 4);
    if (e >= E) return;
    int sub = t & 15;
    int r = rows[e], c = cols[e];
    const float4* qp = (const float4*)(Q + (size_t)r * HD + sub * 8);
    const float4* kp = (const float4*)(Kf + (size_t)c * HD + sub * 8);
    float4 q0 = qp[0], q1 = qp[1];
    float4 k0 = kp[0], k1 = kp[1];
    float p = q0.x * k0.x + q0.y * k0.y + q0.z * k0.z + q0.w * k0.w
            + q1.x * k1.x + q1.y * k1.y + q1.z * k1.z + q1.w * k1.w;
    p += __shfl_xor(p, 1); p += __shfl_xor(p, 2); p += __shfl_xor(p, 4); p += __shfl_xor(p, 8);
    if (sub == 0) {
        float sc = p * 0.08838834764831845f;
        float ls = sc > 0.f ? sc : 0.2f * sc;
        exps[e] = __expf(ls);
    }
}

// row-parallel aggregate + final combine (no cross-lane ops in hot loop)
__global__ void k_aggr(const float* __restrict__ exps, const int* __restrict__ row_ptr,
                       const int* __restrict__ cols, const float* __restrict__ Vf,
                       const float* __restrict__ gate, const float* __restrict__ low,
                       float* __restrict__ high, float* __restrict__ outp, int N) {
    int wid = blockIdx.x * 4 + (threadIdx.x >> 6);
    if (wid >= N) return;
    int lane = threadIdx.x & 63;
    float n0 = 0, n1 = 0, den = 0;
    int s = row_ptr[wid], e = row_ptr[wid + 1];
    int j = s;
    for (; j + 1 < e; j += 2) {
        int c0 = cols[j], c1 = cols[j + 1];
        float e0 = exps[j], e1 = exps[j + 1];
        float2 v0 = *(const float2*)(Vf + (size_t)c0 * HD + lane * 2);
        float2 v1 = *(const float2*)(Vf + (size_t)c1 * HD + lane * 2);
        n0 += e0 * v0.x + e1 * v1.x;
        n1 += e0 * v0.y + e1 * v1.y;
        den += e0 + e1;
    }
    if (j < e) {
        int c0 = cols[j]; float e0 = exps[j];
        float2 v0 = *(const float2*)(Vf + (size_t)c0 * HD + lane * 2);
        n0 += e0 * v0.x; n1 += e0 * v0.y; den += e0;
    }
    float inv = 1.0f / (den + 1e-16f);
    float h0 = n0 * inv, h1 = n1 * inv;
    *(float2*)(high + (size_t)wid * HD + lane * 2) = make_float2(h0, h1);
    float g0 = gate[(size_t)wid * 2 + 0], g1 = gate[(size_t)wid * 2 + 1];
    float2 lw = *(const float2*)(low + (size_t)wid * HD + lane * 2);
    *(float2*)(outp + (size_t)wid * HD + lane * 2) = make_float2(g0 * lw.x + g1 * h0, g0 * lw.y + g1 * h1);
}

// ---------------------------------------------------------------------------
extern "C" void kernel_launch(void* const* d_in, const int* in_sizes, int n_in,
                              void* d_out, int out_size, void* d_ws, size_t ws_size,
                              hipStream_t stream) {
    const float* x      = (const float*)d_in[0];
    const int*   erow   = (const int*)d_in[1];
    const int*   ecol   = (const int*)d_in[2];
    const float* avals  = (const float*)d_in[3];
    const float* W_gc1  = (const float*)d_in[4];
    const float* bn1_g  = (const float*)d_in[6];
    const float* bn1_b  = (const float*)d_in[7];
    const float* W_gc2  = (const float*)d_in[8];
    const float* bn2_g  = (const float*)d_in[10];
    const float* bn2_b  = (const float*)d_in[11];
    const float* Wg1    = (const float*)d_in[12];
    const float* bg1    = (const float*)d_in[13];
    const float* ln_g   = (const float*)d_in[14];
    const float* ln_b   = (const float*)d_in[15];
    const float* Wg2    = (const float*)d_in[16];
    const float* bg2    = (const float*)d_in[17];
    const float* Wxp    = (const float*)d_in[18];
    const float* bxp    = (const float*)d_in[19];
    const float* rscale = (const float*)d_in[20];
    const float* rn_g   = (const float*)d_in[21];
    const float* rn_b   = (const float*)d_in[22];
    const float* Wq     = (const float*)d_in[23];
    const float* Wk     = (const float*)d_in[24];
    const float* Wv     = (const float*)d_in[25];

    const int N = in_sizes[0] / F0;   // 100000
    const int E = in_sizes[1];        // 3200000

    // ---- workspace carve (256B aligned) ----
    char* base = (char*)d_ws;
    size_t off = 0;
    auto carve = [&](size_t bytes) -> char* {
        char* p = base + off;
        off += (bytes + 255) & ~(size_t)255;
        return p;
    };
    double* stats  = (double*)carve(4096);
    float* scaleb  = (float*)carve(1024);
    float* shiftb  = (float*)carve(1024);
    int*   partials= (int*)carve(2048);
    u16* Wgc1t = (u16*)carve(65536 * 2);
    u16* Wgc2t = (u16*)carve(32768 * 2);
    u16* Wdt   = (u16*)carve(32768 * 2);
    u16* W1t   = (u16*)carve(32768 * 2);
    u16* W2t   = (u16*)carve(32768 * 2);
    u16* Wxpt  = (u16*)carve(32768 * 2);
    u16* Wqt   = (u16*)carve(16384 * 2);
    u16* Wkt   = (u16*)carve(16384 * 2);
    u16* Wvt   = (u16*)carve(16384 * 2);
    int*   row_ptr = (int*)carve((size_t)(N + 1) * 4);
    int*   cursor  = (int*)carve((size_t)N * 4);
    float* deg     = (float*)carve((size_t)N * 4);
    int*   row_s   = (int*)carve((size_t)E * 4);
    int*   col_s   = (int*)carve((size_t)E * 4);
    float* val_s   = (float*)carve((size_t)E * 4);      // later reused as exp_s
    u16*   x_bf    = (u16*)carve((size_t)NP * F0 * 2);
    float* AXreg   = (float*)carve((size_t)N * F0 * 4); // AX -> later S2 | Kf | Vf
    u16*   AX_bf   = (u16*)carve((size_t)NP * F0 * 2);
    u16*   XSTD_bf = (u16*)carve((size_t)NP * F0 * 2);
    u16*   h1_bf   = (u16*)carve((size_t)NP * F0 * 2);  // later reused as resid_bf
    float* BIG3    = (float*)carve((size_t)NP * F0 * 4); // AX2 -> S1 -> R0
    u16*   G2_bf   = (u16*)carve((size_t)NP * HD * 2);
    float* M3      = (float*)carve((size_t)NP * HD * 4); // hg -> Q
    (void)ws_size; (void)n_in; (void)out_size;

    float* AX   = AXreg;
    float* S2   = AXreg;                       // dead before Kf/Vf written
    float* Kf   = AXreg;
    float* Vf   = AXreg + (size_t)N * HD;
    u16*   resid_bf = h1_bf;
    float* exps = val_s;

    float* out_o    = (float*)d_out;
    float* out_gate = out_o + (size_t)N * HD;
    float* out_low  = out_gate + (size_t)N * 2;
    float* out_high = out_low + (size_t)N * HD;

    const int eb  = (E + 255) / 256;
    const int wb  = (N + 3) / 4;
    const int NB1 = (N + 1023) / 1024;
    const int gx  = (N + 127) / 128;           // 782
    const dim3 blk(256);

    // ===== CSR =====
    hipMemsetAsync(cursor, 0, (size_t)N * 4, stream);
    k_hist<<<eb, blk, 0, stream>>>(erow, cursor, E);
    k_scan_blk<<<NB1, 1024, 0, stream>>>(cursor, row_ptr + 1, partials, N);
    k_scan_part<<<1, 128, 0, stream>>>(partials, NB1);
    k_scan_add<<<NB1, 1024, 0, stream>>>(row_ptr, partials, N);
    hipMemsetAsync(cursor, 0, (size_t)N * 4, stream);
    k_scatter<<<eb, blk, 0, stream>>>(erow, ecol, avals, row_ptr, cursor, row_s, col_s, val_s, E);

    // ===== casts =====
    k_cast_x<<<(N * 64 + 255) / 256, blk, 0, stream>>>(x, x_bf, N * 64);
    k_prep_w<<<dim3(256, 1, 9), blk, 0, stream>>>(W_gc1, W_gc2, Wg1, Wxp, Wq, Wk, Wv,
                                                  Wgc1t, Wgc2t, Wdt, W1t, W2t, Wxpt, Wqt, Wkt, Wvt);

    // ===== spmm over x =====
    k_spmm_x2<<<wb, blk, 0, stream>>>(x_bf, row_ptr, col_s, val_s, AX, BIG3, deg, N);
    k_finalize<<<(N * 64 + 255) / 256, blk, 0, stream>>>(AX, BIG3, deg, AX_bf, XSTD_bf, N * 64);

    // ===== low path =====
    k_mm_f32<<<dim3(gx, 2), blk, 0, stream>>>(AX_bf, Wgc1t, BIG3, nullptr, N, 256, 256);
    hipMemsetAsync(stats, 0, 4096, stream);
    k_bn_stats<<<1024, blk, 0, stream>>>(BIG3, stats, N, 256);
    k_bn_fin<<<1, blk, 0, stream>>>(stats, bn1_g, bn1_b, scaleb, shiftb, 256, 1.0 / N);
    k_bn_relu_b<<<(N * 64 + 255) / 256, blk, 0, stream>>>(BIG3, h1_bf, scaleb, shiftb, N * 64, 63);
    k_mm_bf<<<dim3(gx, 1), blk, 0, stream>>>(h1_bf, Wgc2t, G2_bf, N, 256, 128);
    k_spmm128<<<wb, blk, 0, stream>>>(G2_bf, row_ptr, col_s, val_s, S2, N);
    hipMemsetAsync(stats, 0, 2048, stream);
    k_bn_stats<<<1024, blk, 0, stream>>>(S2, stats, N, 128);
    k_bn_fin<<<1, blk, 0, stream>>>(stats, bn2_g, bn2_b, scaleb, shiftb, 128, 1.0 / N);
    k_bn_relu_f<<<(N * 32 + 255) / 256, blk, 0, stream>>>(S2, out_low, scaleb, shiftb, N * 32, 31);

    // ===== gating =====
    k_mm_gate<<<dim3(gx, 1), blk, 0, stream>>>(x_bf, AX_bf, XSTD_bf, Wdt, W1t, W2t,
                                               M3, bg1, Wg1 + (size_t)768 * 128, deg, N);
    k_ln_gate<<<wb, blk, 0, stream>>>(M3, ln_g, ln_b, Wg2, bg2, out_gate, N);

    // ===== high path =====
    k_mm_f32<<<dim3(gx, 1), blk, 0, stream>>>(x_bf, Wxpt, BIG3, bxp, N, 256, 128);
    k_resid_ln<<<wb, blk, 0, stream>>>(BIG3, out_low, rn_g, rn_b, rscale, resid_bf, N);
    k_mm_qkv<<<dim3(gx, 1, 3), blk, 0, stream>>>(resid_bf, Wqt, Wkt, Wvt, M3, Kf, Vf, N);
    k_score<<<(E + 15) / 16, blk, 0, stream>>>(M3, Kf, row_s, col_s, exps, E);
    k_aggr<<<wb, blk, 0, stream>>>(exps, row_ptr, col_s, Vf, out_gate, out_low, out_high, out_o, N);
}

// Round 3
// 1827.342 us; speedup vs baseline: 1.8139x; 1.1166x over previous
//
#include <hip/hip_runtime.h>

#define F0 256
#define HD 128
#define NP 100352   // padded rows (784*128)

typedef unsigned short u16;
typedef __attribute__((ext_vector_type(8))) short short8;
typedef __attribute__((ext_vector_type(4))) float f32x4;

__device__ inline float bf2f(u16 u) {
    union { unsigned int i; float f; } v; v.i = ((unsigned int)u) << 16; return v.f;
}
__device__ inline u16 f2bf(float f) {
    union { float f; unsigned int i; } v; v.f = f;
    unsigned int r = v.i + 0x7FFF + ((v.i >> 16) & 1);
    return (u16)(r >> 16);
}

#define GLOAD16(gp, lp) __builtin_amdgcn_global_load_lds( \
    (const __attribute__((address_space(1))) void*)(gp), \
    (__attribute__((address_space(3))) void*)(lp), 16, 0, 0)

// ---------------------------------------------------------------------------
// CSR build (perm-based: scatter 4B edge ids, then coalesced gather)
// ---------------------------------------------------------------------------
__global__ void k_hist(const int* __restrict__ row, int* __restrict__ counts, int E) {
    int e = blockIdx.x * blockDim.x + threadIdx.x;
    if (e < E) atomicAdd(&counts[row[e]], 1);
}

__global__ void k_scan_blk(const int* __restrict__ counts, int* __restrict__ scan_out,
                           int* __restrict__ partials, int n) {
    __shared__ int wsum[16];
    int t = threadIdx.x;
    int i = blockIdx.x * 1024 + t;
    int v = (i < n) ? counts[i] : 0;
    int lane = t & 63, w = t >> 6;
    #pragma unroll
    for (int off = 1; off < 64; off <<= 1) { int u = __shfl_up(v, off); if (lane >= off) v += u; }
    if (lane == 63) wsum[w] = v;
    __syncthreads();
    if (t < 16) {
        int s = wsum[t];
        #pragma unroll
        for (int off = 1; off < 16; off <<= 1) { int u = __shfl_up(s, off); if (t >= off) s += u; }
        wsum[t] = s;
    }
    __syncthreads();
    int add = (w > 0) ? wsum[w - 1] : 0;
    if (i < n) scan_out[i] = v + add;
    if (t == 1023) partials[blockIdx.x] = wsum[15];
}

__global__ void k_scan_part(int* partials, int nb) {
    __shared__ int ws2[2];
    int t = threadIdx.x;
    int v = (t < nb) ? partials[t] : 0;
    int lane = t & 63, w = t >> 6;
    #pragma unroll
    for (int off = 1; off < 64; off <<= 1) { int u = __shfl_up(v, off); if (lane >= off) v += u; }
    if (lane == 63) ws2[w] = v;
    __syncthreads();
    if (w == 1) v += ws2[0];
    if (t < nb) partials[t] = v;
}

__global__ void k_scan_add(int* __restrict__ row_ptr, const int* __restrict__ partials, int n) {
    int b = blockIdx.x;
    int i = b * 1024 + threadIdx.x;
    if (b == 0 && threadIdx.x == 0) row_ptr[0] = 0;
    int add = (b > 0) ? partials[b - 1] : 0;
    if (i < n) row_ptr[1 + i] += add;
}

__global__ void k_scatter_perm(const int* __restrict__ row, const int* __restrict__ row_ptr,
                               int* __restrict__ cursor, int* __restrict__ perm, int E) {
    int e = blockIdx.x * blockDim.x + threadIdx.x;
    if (e >= E) return;
    int r = row[e];
    int pos = row_ptr[r] + atomicAdd(&cursor[r], 1);
    perm[pos] = e;
}

// coalesced writes; random reads hit L2/L3 (12.8MB sources)
__global__ void k_gather_edges(const int* __restrict__ perm, const int* __restrict__ ecol,
                               const float* __restrict__ avals, int* __restrict__ col_s,
                               float* __restrict__ val_s, int E) {
    int i = blockIdx.x * blockDim.x + threadIdx.x;
    if (i >= E) return;
    int e = perm[i];
    col_s[i] = ecol[e];
    val_s[i] = avals[e];
}

__global__ void k_rowfill(const int* __restrict__ row_ptr, int* __restrict__ row_s, int N) {
    int wid = blockIdx.x * 4 + (threadIdx.x >> 6);
    if (wid >= N) return;
    int lane = threadIdx.x & 63;
    int s = row_ptr[wid], e = row_ptr[wid + 1];
    for (int j = s + lane; j < e; j += 64) row_s[j] = wid;
}

// ---------------------------------------------------------------------------
// casts
// ---------------------------------------------------------------------------
__global__ void k_cast_x(const float* __restrict__ x, u16* __restrict__ xb, int total4) {
    int i = blockIdx.x * blockDim.x + threadIdx.x;
    if (i >= total4) return;
    float4 v = ((const float4*)x)[i];
    ((ushort4*)xb)[i] = make_ushort4(f2bf(v.x), f2bf(v.y), f2bf(v.z), f2bf(v.w));
}

__global__ void k_prep_w(const float* __restrict__ W_gc1, const float* __restrict__ W_gc2,
                         const float* __restrict__ Wg1, const float* __restrict__ Wxp,
                         const float* __restrict__ Wq, const float* __restrict__ Wk,
                         const float* __restrict__ Wv,
                         u16* Wgc1t, u16* Wgc2t, u16* Wdt, u16* W1t, u16* W2t,
                         u16* Wxpt, u16* Wqt, u16* Wkt, u16* Wvt) {
    int z = blockIdx.z;
    int idx = blockIdx.x * 256 + threadIdx.x;
    if (z == 0) { if (idx < 65536) { int n = idx >> 8, k = idx & 255; Wgc1t[idx] = f2bf(W_gc1[k * 256 + n]); } }
    else if (z == 1) { if (idx < 32768) { int n = idx >> 8, k = idx & 255; Wgc2t[idx] = f2bf(W_gc2[k * 128 + n]); } }
    else if (z == 2) { if (idx < 32768) { int n = idx >> 8, k = idx & 255; Wdt[idx] = f2bf(Wg1[k * 128 + n] - Wg1[(k + 256) * 128 + n]); } }
    else if (z == 3) { if (idx < 32768) { int n = idx >> 8, k = idx & 255; W1t[idx] = f2bf(Wg1[(k + 256) * 128 + n]); } }
    else if (z == 4) { if (idx < 32768) { int n = idx >> 8, k = idx & 255; W2t[idx] = f2bf(Wg1[(k + 512) * 128 + n]); } }
    else if (z == 5) { if (idx < 32768) { int n = idx >> 8, k = idx & 255; Wxpt[idx] = f2bf(Wxp[k * 128 + n]); } }
    else if (z == 6) { if (idx < 16384) { int n = idx >> 7, k = idx & 127; Wqt[idx] = f2bf(Wq[k * 128 + n]); } }
    else if (z == 7) { if (idx < 16384) { int n = idx >> 7, k = idx & 127; Wkt[idx] = f2bf(Wk[k * 128 + n]); } }
    else if (z == 8) { if (idx < 16384) { int n = idx >> 7, k = idx & 127; Wvt[idx] = f2bf(Wv[k * 128 + n]); } }
}

// ---------------------------------------------------------------------------
// SpMM (bf16 gathers, unroll-4)
// ---------------------------------------------------------------------------
__global__ void k_spmm_x2(const u16* __restrict__ Xb, const int* __restrict__ row_ptr,
                          const int* __restrict__ cols, const float* __restrict__ vals,
                          float* __restrict__ AX, float* __restrict__ AX2,
                          float* __restrict__ deg, int N) {
    int wid = blockIdx.x * 4 + (threadIdx.x >> 6);
    if (wid >= N) return;
    int lane = threadIdx.x & 63;
    float a0 = 0, a1 = 0, a2 = 0, a3 = 0;
    float q0 = 0, q1 = 0, q2 = 0, q3 = 0, d = 0;
    int s = row_ptr[wid], e = row_ptr[wid + 1];
    int j = s;
    for (; j + 3 < e; j += 4) {
        int c[4]; float v[4]; ushort4 xb[4];
        #pragma unroll
        for (int t = 0; t < 4; ++t) { c[t] = cols[j + t]; v[t] = vals[j + t]; }
        #pragma unroll
        for (int t = 0; t < 4; ++t) xb[t] = *(const ushort4*)(Xb + (size_t)c[t] * F0 + lane * 4);
        #pragma unroll
        for (int t = 0; t < 4; ++t) {
            float x0 = bf2f(xb[t].x), x1 = bf2f(xb[t].y), x2 = bf2f(xb[t].z), x3 = bf2f(xb[t].w);
            float vv = v[t];
            a0 += vv * x0; a1 += vv * x1; a2 += vv * x2; a3 += vv * x3;
            q0 += vv * x0 * x0; q1 += vv * x1 * x1; q2 += vv * x2 * x2; q3 += vv * x3 * x3;
            d += vv;
        }
    }
    for (; j < e; ++j) {
        int c0 = cols[j]; float v0 = vals[j];
        ushort4 xb0 = *(const ushort4*)(Xb + (size_t)c0 * F0 + lane * 4);
        float x0 = bf2f(xb0.x), x1 = bf2f(xb0.y), x2 = bf2f(xb0.z), x3 = bf2f(xb0.w);
        a0 += v0 * x0; a1 += v0 * x1; a2 += v0 * x2; a3 += v0 * x3;
        q0 += v0 * x0 * x0; q1 += v0 * x1 * x1; q2 += v0 * x2 * x2; q3 += v0 * x3 * x3;
        d += v0;
    }
    *(float4*)(AX + (size_t)wid * F0 + lane * 4) = make_float4(a0, a1, a2, a3);
    *(float4*)(AX2 + (size_t)wid * F0 + lane * 4) = make_float4(q0, q1, q2, q3);
    if (lane == 0) deg[wid] = d;
}

// bf16 in, bf16 out
__global__ void k_spmm128(const u16* __restrict__ Xb, const int* __restrict__ row_ptr,
                          const int* __restrict__ cols, const float* __restrict__ vals,
                          u16* __restrict__ OUT, int N) {
    int wid = blockIdx.x * 4 + (threadIdx.x >> 6);
    if (wid >= N) return;
    int lane = threadIdx.x & 63;
    float a0 = 0, a1 = 0;
    int s = row_ptr[wid], e = row_ptr[wid + 1];
    int j = s;
    for (; j + 3 < e; j += 4) {
        int c[4]; float v[4]; ushort2 xb[4];
        #pragma unroll
        for (int t = 0; t < 4; ++t) { c[t] = cols[j + t]; v[t] = vals[j + t]; }
        #pragma unroll
        for (int t = 0; t < 4; ++t) xb[t] = *(const ushort2*)(Xb + (size_t)c[t] * HD + lane * 2);
        #pragma unroll
        for (int t = 0; t < 4; ++t) { a0 += v[t] * bf2f(xb[t].x); a1 += v[t] * bf2f(xb[t].y); }
    }
    for (; j < e; ++j) {
        int c0 = cols[j]; float v0 = vals[j];
        ushort2 x0 = *(const ushort2*)(Xb + (size_t)c0 * HD + lane * 2);
        a0 += v0 * bf2f(x0.x); a1 += v0 * bf2f(x0.y);
    }
    *(ushort2*)(OUT + (size_t)wid * HD + lane * 2) = make_ushort2(f2bf(a0), f2bf(a1));
}

// ---------------------------------------------------------------------------
// bf16 MFMA GEMM core: C[128,128] tile = A[M,K] @ Bt[N,K]^T, BK=32
// ---------------------------------------------------------------------------
__device__ inline void mm_core(const u16* __restrict__ A, const u16* __restrict__ Bt,
                               int K, int ldA, int ldB, int m0, int n0,
                               u16* As, u16* Bs, f32x4 acc[4][4]) {
    int t = threadIdx.x, w = t >> 6, l = t & 63;
    int wr = (w >> 1) * 64, wc = (w & 1) * 64;
    int aoff = (wr + (l & 15)) * 32 + (l >> 4) * 8;
    int boff = (wc + (l & 15)) * 32 + (l >> 4) * 8;
    for (int k0 = 0; k0 < K; k0 += 32) {
        __syncthreads();
        #pragma unroll
        for (int s = 0; s < 2; ++s) {
            int i = s * 256 + t;
            int row = i >> 2, ch = i & 3;
            GLOAD16(A + (size_t)(m0 + row) * ldA + k0 + ch * 8, As + i * 8);
            GLOAD16(Bt + (size_t)(n0 + row) * ldB + k0 + ch * 8, Bs + i * 8);
        }
        __syncthreads();
        short8 af[4], bfr[4];
        #pragma unroll
        for (int i = 0; i < 4; ++i) af[i] = *(const short8*)(As + aoff + i * 16 * 32);
        #pragma unroll
        for (int j = 0; j < 4; ++j) bfr[j] = *(const short8*)(Bs + boff + j * 16 * 32);
        #pragma unroll
        for (int i = 0; i < 4; ++i)
            #pragma unroll
            for (int j = 0; j < 4; ++j)
                acc[i][j] = __builtin_amdgcn_mfma_f32_16x16x32_bf16(af[i], bfr[j], acc[i][j], 0, 0, 0);
    }
}

__device__ inline void mm_zero(f32x4 acc[4][4]) {
    #pragma unroll
    for (int i = 0; i < 4; ++i)
        #pragma unroll
        for (int j = 0; j < 4; ++j)
            acc[i][j] = (f32x4){0.f, 0.f, 0.f, 0.f};
}

__global__ __launch_bounds__(256) void k_mm_f32(const u16* __restrict__ A, const u16* __restrict__ Bt,
                                                float* __restrict__ C, const float* __restrict__ bias,
                                                int M, int K, int Nc) {
    __shared__ __align__(16) u16 As[128 * 32];
    __shared__ __align__(16) u16 Bs[128 * 32];
    int m0 = blockIdx.x * 128, n0 = blockIdx.y * 128;
    f32x4 acc[4][4]; mm_zero(acc);
    mm_core(A, Bt, K, K, K, m0, n0, As, Bs, acc);
    int t = threadIdx.x, w = t >> 6, l = t & 63;
    int rbase = m0 + (w >> 1) * 64 + (l >> 4) * 4;
    int cbase = n0 + (w & 1) * 64 + (l & 15);
    #pragma unroll
    for (int j = 0; j < 4; ++j) {
        float bj = bias ? bias[cbase + j * 16] : 0.f;
        #pragma unroll
        for (int i = 0; i < 4; ++i)
            #pragma unroll
            for (int r = 0; r < 4; ++r) {
                int row = rbase + i * 16 + r;
                if (row < M) C[(size_t)row * Nc + cbase + j * 16] = acc[i][j][r] + bj;
            }
    }
}

__global__ __launch_bounds__(256) void k_mm_bf(const u16* __restrict__ A, const u16* __restrict__ Bt,
                                               u16* __restrict__ C, int M, int K, int Nc) {
    __shared__ __align__(16) u16 As[128 * 32];
    __shared__ __align__(16) u16 Bs[128 * 32];
    int m0 = blockIdx.x * 128, n0 = blockIdx.y * 128;
    f32x4 acc[4][4]; mm_zero(acc);
    mm_core(A, Bt, K, K, K, m0, n0, As, Bs, acc);
    int t = threadIdx.x, w = t >> 6, l = t & 63;
    int rbase = m0 + (w >> 1) * 64 + (l >> 4) * 4;
    int cbase = n0 + (w & 1) * 64 + (l & 15);
    #pragma unroll
    for (int j = 0; j < 4; ++j)
        #pragma unroll
        for (int i = 0; i < 4; ++i)
            #pragma unroll
            for (int r = 0; r < 4; ++r) {
                int row = rbase + i * 16 + r;
                if (row < M) C[(size_t)row * Nc + cbase + j * 16] = f2bf(acc[i][j][r]);
            }
}

__global__ __launch_bounds__(256) void k_mm_gate(const u16* A0, const u16* A1, const u16* A2,
                                                 const u16* B0, const u16* B1, const u16* B2,
                                                 float* __restrict__ C, const float* __restrict__ bg1,
                                                 const float* __restrict__ wlast,
                                                 const float* __restrict__ deg, int M) {
    __shared__ __align__(16) u16 As[128 * 32];
    __shared__ __align__(16) u16 Bs[128 * 32];
    int m0 = blockIdx.x * 128;
    f32x4 acc[4][4]; mm_zero(acc);
    mm_core(A0, B0, 256, 256, 256, m0, 0, As, Bs, acc);
    mm_core(A1, B1, 256, 256, 256, m0, 0, As, Bs, acc);
    mm_core(A2, B2, 256, 256, 256, m0, 0, As, Bs, acc);
    int t = threadIdx.x, w = t >> 6, l = t & 63;
    int rbase = m0 + (w >> 1) * 64 + (l >> 4) * 4;
    int cbase = (w & 1) * 64 + (l & 15);
    float wl[4], bg[4];
    #pragma unroll
    for (int j = 0; j < 4; ++j) { wl[j] = wlast[cbase + j * 16]; bg[j] = bg1[cbase + j * 16]; }
    float dg[4][4];
    #pragma unroll
    for (int i = 0; i < 4; ++i)
        #pragma unroll
        for (int r = 0; r < 4; ++r) {
            int row = rbase + i * 16 + r;
            dg[i][r] = (row < M) ? deg[row] : 0.f;
        }
    #pragma unroll
    for (int j = 0; j < 4; ++j)
        #pragma unroll
        for (int i = 0; i < 4; ++i)
            #pragma unroll
            for (int r = 0; r < 4; ++r) {
                int row = rbase + i * 16 + r;
                if (row < M) C[(size_t)row * 128 + cbase + j * 16] = acc[i][j][r] + bg[j] + dg[i][r] * wl[j];
            }
}

// Q -> f32, K/V -> bf16
__global__ __launch_bounds__(256) void k_mm_qkv(const u16* __restrict__ A,
                                                const u16* Wqt, const u16* Wkt, const u16* Wvt,
                                                float* Q, u16* Kb, u16* Vb, int M) {
    __shared__ __align__(16) u16 As[128 * 32];
    __shared__ __align__(16) u16 Bs[128 * 32];
    int z = blockIdx.z;
    const u16* Bt = (z == 0) ? Wqt : (z == 1) ? Wkt : Wvt;
    int m0 = blockIdx.x * 128;
    f32x4 acc[4][4]; mm_zero(acc);
    mm_core(A, Bt, 128, 128, 128, m0, 0, As, Bs, acc);
    int t = threadIdx.x, w = t >> 6, l = t & 63;
    int rbase = m0 + (w >> 1) * 64 + (l >> 4) * 4;
    int cbase = (w & 1) * 64 + (l & 15);
    if (z == 0) {
        #pragma unroll
        for (int j = 0; j < 4; ++j)
            #pragma unroll
            for (int i = 0; i < 4; ++i)
                #pragma unroll
                for (int r = 0; r < 4; ++r) {
                    int row = rbase + i * 16 + r;
                    if (row < M) Q[(size_t)row * 128 + cbase + j * 16] = acc[i][j][r];
                }
    } else {
        u16* C = (z == 1) ? Kb : Vb;
        #pragma unroll
        for (int j = 0; j < 4; ++j)
            #pragma unroll
            for (int i = 0; i < 4; ++i)
                #pragma unroll
                for (int r = 0; r < 4; ++r) {
                    int row = rbase + i * 16 + r;
                    if (row < M) C[(size_t)row * 128 + cbase + j * 16] = f2bf(acc[i][j][r]);
                }
    }
}

// ---------------------------------------------------------------------------
// BatchNorm (bf16 input)
// ---------------------------------------------------------------------------
__global__ void k_bn_stats_bf(const u16* __restrict__ H, double* __restrict__ stats, int N, int C) {
    int t = threadIdx.x;
    int rpt = 256 / C;
    int rsub = t / C;
    int col = t - rsub * C;
    double s = 0.0, q = 0.0;
    for (long r = (long)blockIdx.x * rpt + rsub; r < N; r += (long)gridDim.x * rpt) {
        float v = bf2f(H[(size_t)r * C + col]);
        s += v; q += (double)v * v;
    }
    __shared__ double sh_s[256], sh_q[256];
    sh_s[t] = s; sh_q[t] = q;
    __syncthreads();
    if (t < C) {
        for (int k = 1; k < rpt; ++k) { s += sh_s[t + k * C]; q += sh_q[t + k * C]; }
        atomicAdd(&stats[t], s);
        atomicAdd(&stats[C + t], q);
    }
}

__global__ void k_bn_fin(const double* __restrict__ stats, const float* __restrict__ g,
                         const float* __restrict__ b, float* __restrict__ scale,
                         float* __restrict__ shift, int C, double invN) {
    int t = threadIdx.x;
    if (t >= C) return;
    double mean = stats[t] * invN;
    double var = stats[C + t] * invN - mean * mean;
    float sc = (float)((double)g[t] / sqrt(var + 1e-5));
    scale[t] = sc;
    shift[t] = b[t] - (float)mean * sc;
}

// bf16 -> bf16 (in-place ok)
__global__ void k_bn_relu_bb(const u16* __restrict__ in, u16* __restrict__ out,
                             const float* __restrict__ scale, const float* __restrict__ shift,
                             int total4, int cmask4) {
    int i = blockIdx.x * blockDim.x + threadIdx.x;
    if (i >= total4) return;
    int c4 = i & cmask4;
    ushort4 v = ((const ushort4*)in)[i];
    float4 sc = ((const float4*)scale)[c4];
    float4 sh = ((const float4*)shift)[c4];
    ((ushort4*)out)[i] = make_ushort4(
        f2bf(fmaxf(bf2f(v.x) * sc.x + sh.x, 0.f)), f2bf(fmaxf(bf2f(v.y) * sc.y + sh.y, 0.f)),
        f2bf(fmaxf(bf2f(v.z) * sc.z + sh.z, 0.f)), f2bf(fmaxf(bf2f(v.w) * sc.w + sh.w, 0.f)));
}

// bf16 -> f32
__global__ void k_bn_relu_bf(const u16* __restrict__ in, float* __restrict__ out,
                             const float* __restrict__ scale, const float* __restrict__ shift,
                             int total4, int cmask4) {
    int i = blockIdx.x * blockDim.x + threadIdx.x;
    if (i >= total4) return;
    int c4 = i & cmask4;
    ushort4 v = ((const ushort4*)in)[i];
    float4 sc = ((const float4*)scale)[c4];
    float4 sh = ((const float4*)shift)[c4];
    ((float4*)out)[i] = make_float4(
        fmaxf(bf2f(v.x) * sc.x + sh.x, 0.f), fmaxf(bf2f(v.y) * sc.y + sh.y, 0.f),
        fmaxf(bf2f(v.z) * sc.z + sh.z, 0.f), fmaxf(bf2f(v.w) * sc.w + sh.w, 0.f));
}

// ---------------------------------------------------------------------------
// gating helpers
// ---------------------------------------------------------------------------
__global__ void k_finalize(const float* __restrict__ AX, const float* __restrict__ AX2,
                           const float* __restrict__ deg, u16* __restrict__ AXb,
                           u16* __restrict__ XSTDb, int total4) {
    int i = blockIdx.x * blockDim.x + threadIdx.x;
    if (i >= total4) return;
    int r = i >> 6;
    float inv = 1.0f / (deg[r] + 1e-8f);
    float4 ax = ((const float4*)AX)[i];
    float4 a2 = ((const float4*)AX2)[i];
    float mx = ax.x * inv, my = ax.y * inv, mz = ax.z * inv, mw = ax.w * inv;
    float sx = sqrtf(fmaxf(a2.x * inv - mx * mx, 0.f));
    float sy = sqrtf(fmaxf(a2.y * inv - my * my, 0.f));
    float sz = sqrtf(fmaxf(a2.z * inv - mz * mz, 0.f));
    float sw = sqrtf(fmaxf(a2.w * inv - mw * mw, 0.f));
    ((ushort4*)AXb)[i] = make_ushort4(f2bf(ax.x), f2bf(ax.y), f2bf(ax.z), f2bf(ax.w));
    ((ushort4*)XSTDb)[i] = make_ushort4(f2bf(sx), f2bf(sy), f2bf(sz), f2bf(sw));
}

__global__ void k_ln_gate(const float* __restrict__ Hg, const float* __restrict__ g,
                          const float* __restrict__ b, const float* __restrict__ Wg2,
                          const float* __restrict__ bg2, float* __restrict__ gate, int N) {
    int wid = blockIdx.x * 4 + (threadIdx.x >> 6);
    if (wid >= N) return;
    int lane = threadIdx.x & 63;
    float2 h = *(const float2*)(Hg + (size_t)wid * HD + lane * 2);
    float s1 = h.x + h.y, s2 = h.x * h.x + h.y * h.y;
    #pragma unroll
    for (int off = 32; off > 0; off >>= 1) { s1 += __shfl_xor(s1, off); s2 += __shfl_xor(s2, off); }
    float mu = s1 * (1.f / 128.f);
    float var = s2 * (1.f / 128.f) - mu * mu;
    float is = 1.0f / sqrtf(var + 1e-5f);
    float2 gg = *(const float2*)(g + lane * 2);
    float2 bb = *(const float2*)(b + lane * 2);
    float y0 = fmaxf((h.x - mu) * is * gg.x + bb.x, 0.f);
    float y1 = fmaxf((h.y - mu) * is * gg.y + bb.y, 0.f);
    float4 w = ((const float4*)Wg2)[lane];
    float t0 = y0 * w.x + y1 * w.z;
    float t1 = y0 * w.y + y1 * w.w;
    #pragma unroll
    for (int off = 32; off > 0; off >>= 1) { t0 += __shfl_xor(t0, off); t1 += __shfl_xor(t1, off); }
    if (lane == 0) {
        t0 = (t0 + bg2[0]) * 0.5f;
        t1 = (t1 + bg2[1]) * 0.5f;
        float m = fmaxf(t0, t1);
        float e0 = __expf(t0 - m), e1 = __expf(t1 - m);
        float inv = 1.0f / (e0 + e1);
        gate[(size_t)wid * 2 + 0] = e0 * inv;
        gate[(size_t)wid * 2 + 1] = e1 * inv;
    }
}

__global__ void k_resid_ln(const float* __restrict__ R0, const float* __restrict__ low,
                           const float* __restrict__ g, const float* __restrict__ b,
                           const float* __restrict__ rs_ptr, u16* __restrict__ resid, int N) {
    int wid = blockIdx.x * 4 + (threadIdx.x >> 6);
    if (wid >= N) return;
    int lane = threadIdx.x & 63;
    float rs = rs_ptr[0];
    float2 a = *(const float2*)(R0 + (size_t)wid * HD + lane * 2);
    float2 l = *(const float2*)(low + (size_t)wid * HD + lane * 2);
    float h0 = rs * (a.x - l.x), h1 = rs * (a.y - l.y);
    float s1 = h0 + h1, s2 = h0 * h0 + h1 * h1;
    #pragma unroll
    for (int off = 32; off > 0; off >>= 1) { s1 += __shfl_xor(s1, off); s2 += __shfl_xor(s2, off); }
    float mu = s1 * (1.f / 128.f);
    float var = s2 * (1.f / 128.f) - mu * mu;
    float is = 1.0f / sqrtf(var + 1e-5f);
    float2 gg = *(const float2*)(g + lane * 2);
    float2 bb = *(const float2*)(b + lane * 2);
    float y0 = (h0 - mu) * is * gg.x + bb.x;
    float y1 = (h1 - mu) * is * gg.y + bb.y;
    *(ushort2*)(resid + (size_t)wid * HD + lane * 2) = make_ushort2(f2bf(y0), f2bf(y1));
}

// edge-parallel scores: 16 lanes per edge; K in bf16
__global__ void k_score(const float* __restrict__ Q, const u16* __restrict__ Kb,
                        const int* __restrict__ rows, const int* __restrict__ cols,
                        float* __restrict__ exps, int E) {
    int t = threadIdx.x;
    int e = blockIdx.x * 16 + (t >> 4);
    if (e >= E) return;
    int sub = t & 15;
    int r = rows[e], c = cols[e];
    const float4* qp = (const float4*)(Q + (size_t)r * HD + sub * 8);
    float4 q0 = qp[0], q1 = qp[1];
    ushort4 k0 = *(const ushort4*)(Kb + (size_t)c * HD + sub * 8);
    ushort4 k1 = *(const ushort4*)(Kb + (size_t)c * HD + sub * 8 + 4);
    float p = q0.x * bf2f(k0.x) + q0.y * bf2f(k0.y) + q0.z * bf2f(k0.z) + q0.w * bf2f(k0.w)
            + q1.x * bf2f(k1.x) + q1.y * bf2f(k1.y) + q1.z * bf2f(k1.z) + q1.w * bf2f(k1.w);
    p += __shfl_xor(p, 1); p += __shfl_xor(p, 2); p += __shfl_xor(p, 4); p += __shfl_xor(p, 8);
    if (sub == 0) {
        float sc = p * 0.08838834764831845f;
        float ls = sc > 0.f ? sc : 0.2f * sc;
        exps[e] = __expf(ls);
    }
}

// row-parallel aggregate + combine; V in bf16, unroll-4
__global__ void k_aggr(const float* __restrict__ exps, const int* __restrict__ row_ptr,
                       const int* __restrict__ cols, const u16* __restrict__ Vb,
                       const float* __restrict__ gate, const float* __restrict__ low,
                       float* __restrict__ high, float* __restrict__ outp, int N) {
    int wid = blockIdx.x * 4 + (threadIdx.x >> 6);
    if (wid >= N) return;
    int lane = threadIdx.x & 63;
    float n0 = 0, n1 = 0, den = 0;
    int s = row_ptr[wid], e = row_ptr[wid + 1];
    int j = s;
    for (; j + 3 < e; j += 4) {
        int c[4]; float ee[4]; ushort2 vb[4];
        #pragma unroll
        for (int t = 0; t < 4; ++t) { c[t] = cols[j + t]; ee[t] = exps[j + t]; }
        #pragma unroll
        for (int t = 0; t < 4; ++t) vb[t] = *(const ushort2*)(Vb + (size_t)c[t] * HD + lane * 2);
        #pragma unroll
        for (int t = 0; t < 4; ++t) {
            n0 += ee[t] * bf2f(vb[t].x);
            n1 += ee[t] * bf2f(vb[t].y);
            den += ee[t];
        }
    }
    for (; j < e; ++j) {
        int c0 = cols[j]; float e0 = exps[j];
        ushort2 v0 = *(const ushort2*)(Vb + (size_t)c0 * HD + lane * 2);
        n0 += e0 * bf2f(v0.x); n1 += e0 * bf2f(v0.y); den += e0;
    }
    float inv = 1.0f / (den + 1e-16f);
    float h0 = n0 * inv, h1 = n1 * inv;
    *(float2*)(high + (size_t)wid * HD + lane * 2) = make_float2(h0, h1);
    float g0 = gate[(size_t)wid * 2 + 0], g1 = gate[(size_t)wid * 2 + 1];
    float2 lw = *(const float2*)(low + (size_t)wid * HD + lane * 2);
    *(float2*)(outp + (size_t)wid * HD + lane * 2) = make_float2(g0 * lw.x + g1 * h0, g0 * lw.y + g1 * h1);
}

// ---------------------------------------------------------------------------
extern "C" void kernel_launch(void* const* d_in, const int* in_sizes, int n_in,
                              void* d_out, int out_size, void* d_ws, size_t ws_size,
                              hipStream_t stream) {
    const float* x      = (const float*)d_in[0];
    const int*   erow   = (const int*)d_in[1];
    const int*   ecol   = (const int*)d_in[2];
    const float* avals  = (const float*)d_in[3];
    const float* W_gc1  = (const float*)d_in[4];
    const float* bn1_g  = (const float*)d_in[6];
    const float* bn1_b  = (const float*)d_in[7];
    const float* W_gc2  = (const float*)d_in[8];
    const float* bn2_g  = (const float*)d_in[10];
    const float* bn2_b  = (const float*)d_in[11];
    const float* Wg1    = (const float*)d_in[12];
    const float* bg1    = (const float*)d_in[13];
    const float* ln_g   = (const float*)d_in[14];
    const float* ln_b   = (const float*)d_in[15];
    const float* Wg2    = (const float*)d_in[16];
    const float* bg2    = (const float*)d_in[17];
    const float* Wxp    = (const float*)d_in[18];
    const float* bxp    = (const float*)d_in[19];
    const float* rscale = (const float*)d_in[20];
    const float* rn_g   = (const float*)d_in[21];
    const float* rn_b   = (const float*)d_in[22];
    const float* Wq     = (const float*)d_in[23];
    const float* Wk     = (const float*)d_in[24];
    const float* Wv     = (const float*)d_in[25];

    const int N = in_sizes[0] / F0;   // 100000
    const int E = in_sizes[1];        // 3200000

    char* base = (char*)d_ws;
    size_t off = 0;
    auto carve = [&](size_t bytes) -> char* {
        char* p = base + off;
        off += (bytes + 255) & ~(size_t)255;
        return p;
    };
    double* stats  = (double*)carve(4096);
    float* scaleb  = (float*)carve(1024);
    float* shiftb  = (float*)carve(1024);
    int*   partials= (int*)carve(2048);
    u16* Wgc1t = (u16*)carve(65536 * 2);
    u16* Wgc2t = (u16*)carve(32768 * 2);
    u16* Wdt   = (u16*)carve(32768 * 2);
    u16* W1t   = (u16*)carve(32768 * 2);
    u16* W2t   = (u16*)carve(32768 * 2);
    u16* Wxpt  = (u16*)carve(32768 * 2);
    u16* Wqt   = (u16*)carve(16384 * 2);
    u16* Wkt   = (u16*)carve(16384 * 2);
    u16* Wvt   = (u16*)carve(16384 * 2);
    int*   row_ptr = (int*)carve((size_t)(N + 1) * 4);
    int*   cursor  = (int*)carve((size_t)N * 4);
    float* deg     = (float*)carve((size_t)N * 4);
    int*   row_s   = (int*)carve((size_t)E * 4);
    int*   col_s   = (int*)carve((size_t)E * 4);
    float* val_s   = (float*)carve((size_t)E * 4);       // later reused as exp_s
    u16*   x_bf    = (u16*)carve((size_t)NP * F0 * 2);
    float* AXreg   = (float*)carve((size_t)NP * F0 * 4); // AX f32 -> later Kb|Vb (bf16)
    u16*   AX_bf   = (u16*)carve((size_t)NP * F0 * 2);
    u16*   XSTD_bf = (u16*)carve((size_t)NP * F0 * 2);
    u16*   h1_bf   = (u16*)carve((size_t)NP * F0 * 2);   // S1 bf16 -> h1 -> resid
    float* BIG3    = (float*)carve((size_t)NP * F0 * 4); // AX2 -> S2(bf16) -> R0
    u16*   G2_bf   = (u16*)carve((size_t)NP * HD * 2);
    float* M3      = (float*)carve((size_t)NP * HD * 4); // perm -> hg -> Q
    (void)ws_size; (void)n_in; (void)out_size;

    float* AX    = AXreg;
    u16*   Kb    = (u16*)AXreg;                    // AX dead after k_finalize
    u16*   Vb    = (u16*)AXreg + (size_t)N * HD;
    u16*   S1_bf = h1_bf;
    u16*   S2_bf = (u16*)BIG3;                     // dead before R0 written
    u16*   resid_bf = h1_bf;                       // h1 dead after gc2 GEMM
    float* exps  = val_s;                          // val_s dead after spmm128
    int*   perm  = (int*)M3;                       // M3 unused during CSR build

    float* out_o    = (float*)d_out;
    float* out_gate = out_o + (size_t)N * HD;
    float* out_low  = out_gate + (size_t)N * 2;
    float* out_high = out_low + (size_t)N * HD;

    const int eb  = (E + 255) / 256;
    const int wb  = (N + 3) / 4;
    const int NB1 = (N + 1023) / 1024;
    const int gx  = (N + 127) / 128;
    const dim3 blk(256);

    // ===== CSR (perm-based) =====
    hipMemsetAsync(cursor, 0, (size_t)N * 4, stream);
    k_hist<<<eb, blk, 0, stream>>>(erow, cursor, E);
    k_scan_blk<<<NB1, 1024, 0, stream>>>(cursor, row_ptr + 1, partials, N);
    k_scan_part<<<1, 128, 0, stream>>>(partials, NB1);
    k_scan_add<<<NB1, 1024, 0, stream>>>(row_ptr, partials, N);
    hipMemsetAsync(cursor, 0, (size_t)N * 4, stream);
    k_scatter_perm<<<eb, blk, 0, stream>>>(erow, row_ptr, cursor, perm, E);
    k_gather_edges<<<eb, blk, 0, stream>>>(perm, ecol, avals, col_s, val_s, E);
    k_rowfill<<<wb, blk, 0, stream>>>(row_ptr, row_s, N);

    // ===== casts =====
    k_cast_x<<<(N * 64 + 255) / 256, blk, 0, stream>>>(x, x_bf, N * 64);
    k_prep_w<<<dim3(256, 1, 9), blk, 0, stream>>>(W_gc1, W_gc2, Wg1, Wxp, Wq, Wk, Wv,
                                                  Wgc1t, Wgc2t, Wdt, W1t, W2t, Wxpt, Wqt, Wkt, Wvt);

    // ===== spmm over x =====
    k_spmm_x2<<<wb, blk, 0, stream>>>(x_bf, row_ptr, col_s, val_s, AX, BIG3, deg, N);
    k_finalize<<<(N * 64 + 255) / 256, blk, 0, stream>>>(AX, BIG3, deg, AX_bf, XSTD_bf, N * 64);

    // ===== low path =====
    k_mm_bf<<<dim3(gx, 2), blk, 0, stream>>>(AX_bf, Wgc1t, S1_bf, N, 256, 256);
    hipMemsetAsync(stats, 0, 4096, stream);
    k_bn_stats_bf<<<1024, blk, 0, stream>>>(S1_bf, stats, N, 256);
    k_bn_fin<<<1, blk, 0, stream>>>(stats, bn1_g, bn1_b, scaleb, shiftb, 256, 1.0 / N);
    k_bn_relu_bb<<<(N * 64 + 255) / 256, blk, 0, stream>>>(S1_bf, h1_bf, scaleb, shiftb, N * 64, 63);
    k_mm_bf<<<dim3(gx, 1), blk, 0, stream>>>(h1_bf, Wgc2t, G2_bf, N, 256, 128);
    k_spmm128<<<wb, blk, 0, stream>>>(G2_bf, row_ptr, col_s, val_s, S2_bf, N);
    hipMemsetAsync(stats, 0, 2048, stream);
    k_bn_stats_bf<<<1024, blk, 0, stream>>>(S2_bf, stats, N, 128);
    k_bn_fin<<<1, blk, 0, stream>>>(stats, bn2_g, bn2_b, scaleb, shiftb, 128, 1.0 / N);
    k_bn_relu_bf<<<(N * 32 + 255) / 256, blk, 0, stream>>>(S2_bf, out_low, scaleb, shiftb, N * 32, 31);

    // ===== gating =====
    k_mm_gate<<<dim3(gx, 1), blk, 0, stream>>>(x_bf, AX_bf, XSTD_bf, Wdt, W1t, W2t,
                                               M3, bg1, Wg1 + (size_t)768 * 128, deg, N);
    k_ln_gate<<<wb, blk, 0, stream>>>(M3, ln_g, ln_b, Wg2, bg2, out_gate, N);

    // ===== high path =====
    k_mm_f32<<<dim3(gx, 1), blk, 0, stream>>>(x_bf, Wxpt, BIG3, bxp, N, 256, 128);  // R0
    k_resid_ln<<<wb, blk, 0, stream>>>(BIG3, out_low, rn_g, rn_b, rscale, resid_bf, N);
    k_mm_qkv<<<dim3(gx, 1, 3), blk, 0, stream>>>(resid_bf, Wqt, Wkt, Wvt, M3, Kb, Vb, N);
    k_score<<<(E + 15) / 16, blk, 0, stream>>>(M3, Kb, row_s, col_s, exps, E);
    k_aggr<<<wb, blk, 0, stream>>>(exps, row_ptr, col_s, Vb, out_gate, out_low, out_high, out_o, N);
}